// Round 1
// baseline (2958.117 us; speedup 1.0000x reference)
//
#include <hip/hip_runtime.h>
#include <hip/hip_bf16.h>
#include <math.h>

#define IN_DIM   128
#define HEADS    2
#define OUT_DIM  64
#define OCOLS    128   // HEADS*OUT_DIM
#define NB_A     1024  // blocks for alpha/softmax partial pass

// ---------------- GEMM: h[N,128] = x[N,128] @ W[128,128] ----------------
// Block: 256 threads = 16 rowgroups x 16 colgroups; tile 64 rows x 128 cols.
// W staged in LDS (64KB). Each thread: 4 rows x 8 cols register tile.
__global__ __launch_bounds__(256) void gemm_kernel(
    const float* __restrict__ x, const float* __restrict__ W,
    float* __restrict__ h, int N) {
  __shared__ float Ws[IN_DIM * OCOLS];  // 64 KB
  const int tid = threadIdx.x;
  for (int i = tid * 4; i < IN_DIM * OCOLS; i += 256 * 4) {
    *(float4*)&Ws[i] = *(const float4*)&W[i];
  }
  __syncthreads();

  const int rg = tid >> 4;       // 0..15
  const int cg = tid & 15;       // 0..15
  const int r0 = blockIdx.x * 64 + rg * 4;
  const int c0 = cg * 8;

  float acc[4][8];
#pragma unroll
  for (int r = 0; r < 4; r++)
#pragma unroll
    for (int c = 0; c < 8; c++) acc[r][c] = 0.f;

  for (int k = 0; k < IN_DIM; k += 4) {
    float4 xr[4];
#pragma unroll
    for (int r = 0; r < 4; r++) {
      int row = r0 + r;
      xr[r] = (row < N) ? *(const float4*)&x[(size_t)row * IN_DIM + k]
                        : make_float4(0.f, 0.f, 0.f, 0.f);
    }
#pragma unroll
    for (int kk = 0; kk < 4; kk++) {
      float4 w0 = *(float4*)&Ws[(k + kk) * OCOLS + c0];
      float4 w1 = *(float4*)&Ws[(k + kk) * OCOLS + c0 + 4];
#pragma unroll
      for (int r = 0; r < 4; r++) {
        float xk = (kk == 0) ? xr[r].x : (kk == 1) ? xr[r].y
                  : (kk == 2) ? xr[r].z : xr[r].w;
        acc[r][0] += xk * w0.x; acc[r][1] += xk * w0.y;
        acc[r][2] += xk * w0.z; acc[r][3] += xk * w0.w;
        acc[r][4] += xk * w1.x; acc[r][5] += xk * w1.y;
        acc[r][6] += xk * w1.z; acc[r][7] += xk * w1.w;
      }
    }
  }
#pragma unroll
  for (int r = 0; r < 4; r++) {
    int row = r0 + r;
    if (row < N) {
      *(float4*)&h[(size_t)row * OCOLS + c0]     = make_float4(acc[r][0], acc[r][1], acc[r][2], acc[r][3]);
      *(float4*)&h[(size_t)row * OCOLS + c0 + 4] = make_float4(acc[r][4], acc[r][5], acc[r][6], acc[r][7]);
    }
  }
}

// ------------- per-node attention scalars: alr[n] = {al0, al1, ar0, ar1} ---
// one wave (64 lanes) per node
__global__ __launch_bounds__(256) void alr_kernel(
    const float* __restrict__ h, const float* __restrict__ attn_l,
    const float* __restrict__ attn_r, float* __restrict__ alr, int N) {
  int gid = blockIdx.x * blockDim.x + threadIdx.x;
  int node = gid >> 6;
  int lane = threadIdx.x & 63;
  if (node >= N) return;
  float h0 = h[(size_t)node * OCOLS + lane];        // head 0, d = lane
  float h1 = h[(size_t)node * OCOLS + 64 + lane];   // head 1, d = lane
  float pl0 = h0 * attn_l[lane];
  float pl1 = h1 * attn_l[64 + lane];
  float pr0 = h0 * attn_r[lane];
  float pr1 = h1 * attn_r[64 + lane];
#pragma unroll
  for (int off = 32; off > 0; off >>= 1) {
    pl0 += __shfl_down(pl0, off);
    pl1 += __shfl_down(pl1, off);
    pr0 += __shfl_down(pr0, off);
    pr1 += __shfl_down(pr1, off);
  }
  if (lane == 0) {
    float4 v = make_float4(pl0, pl1, pr0, pr1);
    *(float4*)&alr[(size_t)node * 4] = v;
  }
}

// combiner for online softmax state (m, s)
__device__ inline void softmax_comb(float& m, float& s, float m2, float s2) {
  float M = fmaxf(m, m2);
  s = s * expf(m - M) + s2 * expf(m2 - M);
  m = M;
}

// ---- alpha[e,h] = leakyrelu(al[src]+ar[dst]); per-block online (m,s) ----
__global__ __launch_bounds__(256) void alpha_kernel(
    const int* __restrict__ src, const int* __restrict__ dst,
    const float* __restrict__ alr, float* __restrict__ alpha,
    float* __restrict__ partials, int E) {
  float m0 = -1e30f, s0 = 0.f, m1 = -1e30f, s1 = 0.f;
  for (int e = blockIdx.x * 256 + threadIdx.x; e < E; e += gridDim.x * 256) {
    int sn = src[e], dn = dst[e];
    float4 as = *(const float4*)&alr[(size_t)sn * 4];
    float4 ad = *(const float4*)&alr[(size_t)dn * 4];
    float a0 = as.x + ad.z;
    float a1 = as.y + ad.w;
    a0 = (a0 > 0.f) ? a0 : 0.2f * a0;
    a1 = (a1 > 0.f) ? a1 : 0.2f * a1;
    alpha[(size_t)e * 2]     = a0;
    alpha[(size_t)e * 2 + 1] = a1;
    // online softmax update
    {
      float M = fmaxf(m0, a0);
      s0 = s0 * expf(m0 - M) + expf(a0 - M);
      m0 = M;
    }
    {
      float M = fmaxf(m1, a1);
      s1 = s1 * expf(m1 - M) + expf(a1 - M);
      m1 = M;
    }
  }
  // wave reduce
#pragma unroll
  for (int off = 1; off < 64; off <<= 1) {
    float m0o = __shfl_xor(m0, off), s0o = __shfl_xor(s0, off);
    float m1o = __shfl_xor(m1, off), s1o = __shfl_xor(s1, off);
    softmax_comb(m0, s0, m0o, s0o);
    softmax_comb(m1, s1, m1o, s1o);
  }
  __shared__ float red[4][4];
  int wave = threadIdx.x >> 6;
  int lane = threadIdx.x & 63;
  if (lane == 0) {
    red[wave][0] = m0; red[wave][1] = s0; red[wave][2] = m1; red[wave][3] = s1;
  }
  __syncthreads();
  if (threadIdx.x == 0) {
    float M0 = red[0][0], S0 = red[0][1], M1 = red[0][2], S1 = red[0][3];
    for (int w = 1; w < 4; w++) {
      softmax_comb(M0, S0, red[w][0], red[w][1]);
      softmax_comb(M1, S1, red[w][2], red[w][3]);
    }
    float* p = &partials[(size_t)blockIdx.x * 4];
    p[0] = M0; p[1] = S0; p[2] = M1; p[3] = S1;
  }
}

// ---- combine NB_A partials -> stats {M0, 1/S0, M1, 1/S1} ----
__global__ __launch_bounds__(256) void reduce_kernel(
    const float* __restrict__ partials, float* __restrict__ stats) {
  float m0 = -1e30f, s0 = 0.f, m1 = -1e30f, s1 = 0.f;
  for (int i = threadIdx.x; i < NB_A; i += 256) {
    const float* p = &partials[(size_t)i * 4];
    softmax_comb(m0, s0, p[0], p[1]);
    softmax_comb(m1, s1, p[2], p[3]);
  }
#pragma unroll
  for (int off = 1; off < 64; off <<= 1) {
    float m0o = __shfl_xor(m0, off), s0o = __shfl_xor(s0, off);
    float m1o = __shfl_xor(m1, off), s1o = __shfl_xor(s1, off);
    softmax_comb(m0, s0, m0o, s0o);
    softmax_comb(m1, s1, m1o, s1o);
  }
  __shared__ float red[4][4];
  int wave = threadIdx.x >> 6;
  int lane = threadIdx.x & 63;
  if (lane == 0) {
    red[wave][0] = m0; red[wave][1] = s0; red[wave][2] = m1; red[wave][3] = s1;
  }
  __syncthreads();
  if (threadIdx.x == 0) {
    float M0 = red[0][0], S0 = red[0][1], M1 = red[0][2], S1 = red[0][3];
    for (int w = 1; w < 4; w++) {
      softmax_comb(M0, S0, red[w][0], red[w][1]);
      softmax_comb(M1, S1, red[w][2], red[w][3]);
    }
    stats[0] = M0; stats[1] = 1.f / S0;
    stats[2] = M1; stats[3] = 1.f / S1;
  }
}

// ---- scatter: out[dst] += w_eh * h[src];  32 lanes per edge, float4/lane ----
__global__ __launch_bounds__(256) void scatter_kernel(
    const int* __restrict__ src, const int* __restrict__ dst,
    const float* __restrict__ alpha, const float* __restrict__ stats,
    const float* __restrict__ h, float* __restrict__ out, int E) {
  int gid = blockIdx.x * 256 + threadIdx.x;
  int e = gid >> 5;
  if (e >= E) return;
  int l = gid & 31;            // covers floats [l*4, l*4+4)
  int head = l >> 4;           // floats 0..63 head0, 64..127 head1
  int sn = src[e], dn = dst[e];
  float a = alpha[(size_t)e * 2 + head];
  float w = expf(a - stats[head * 2]) * stats[head * 2 + 1];
  float4 hv = *(const float4*)&h[(size_t)sn * OCOLS + l * 4];
  float* op = &out[(size_t)dn * OCOLS + l * 4];
  atomicAdd(op + 0, w * hv.x);
  atomicAdd(op + 1, w * hv.y);
  atomicAdd(op + 2, w * hv.z);
  atomicAdd(op + 3, w * hv.w);
}

extern "C" void kernel_launch(void* const* d_in, const int* in_sizes, int n_in,
                              void* d_out, int out_size, void* d_ws, size_t ws_size,
                              hipStream_t stream) {
  const float* x      = (const float*)d_in[0];
  const int*   edge   = (const int*)d_in[1];   // [2, E]
  const float* W      = (const float*)d_in[2];
  const float* attn_l = (const float*)d_in[3];
  const float* attn_r = (const float*)d_in[4];

  const int N = in_sizes[0] / IN_DIM;
  const int E = in_sizes[1] / 2;
  const int* src = edge;
  const int* dst = edge + E;
  float* out = (float*)d_out;

  // workspace layout
  float* h        = (float*)d_ws;                 // N*128
  float* alr      = h + (size_t)N * OCOLS;        // N*4
  float* alpha    = alr + (size_t)N * 4;          // E*2
  float* partials = alpha + (size_t)E * 2;        // NB_A*4
  float* stats    = partials + (size_t)NB_A * 4;  // 4

  hipMemsetAsync(d_out, 0, (size_t)out_size * sizeof(float), stream);

  gemm_kernel<<<(N + 63) / 64, 256, 0, stream>>>(x, W, h, N);
  alr_kernel<<<((size_t)N * 64 + 255) / 256, 256, 0, stream>>>(h, attn_l, attn_r, alr, N);
  alpha_kernel<<<NB_A, 256, 0, stream>>>(src, dst, alr, alpha, partials, E);
  reduce_kernel<<<1, 256, 0, stream>>>(partials, stats);
  scatter_kernel<<<((size_t)E * 32 + 255) / 256, 256, 0, stream>>>(
      src, dst, alpha, stats, h, out, E);
}

// Round 2
// 792.942 us; speedup vs baseline: 3.7306x; 3.7306x over previous
//
#include <hip/hip_runtime.h>
#include <hip/hip_bf16.h>
#include <math.h>

#define IN_DIM   128
#define HEADS    2
#define OUT_DIM  64
#define OCOLS    128   // HEADS*OUT_DIM
#define NB_A     1024  // blocks for alpha/softmax partial pass

// ---------------- GEMM: h[N,128] = x[N,128] @ W[128,128] ----------------
__global__ __launch_bounds__(256) void gemm_kernel(
    const float* __restrict__ x, const float* __restrict__ W,
    float* __restrict__ h, int N) {
  __shared__ float Ws[IN_DIM * OCOLS];  // 64 KB
  const int tid = threadIdx.x;
  for (int i = tid * 4; i < IN_DIM * OCOLS; i += 256 * 4) {
    *(float4*)&Ws[i] = *(const float4*)&W[i];
  }
  __syncthreads();

  const int rg = tid >> 4;       // 0..15
  const int cg = tid & 15;       // 0..15
  const int r0 = blockIdx.x * 64 + rg * 4;
  const int c0 = cg * 8;

  float acc[4][8];
#pragma unroll
  for (int r = 0; r < 4; r++)
#pragma unroll
    for (int c = 0; c < 8; c++) acc[r][c] = 0.f;

  for (int k = 0; k < IN_DIM; k += 4) {
    float4 xr[4];
#pragma unroll
    for (int r = 0; r < 4; r++) {
      int row = r0 + r;
      xr[r] = (row < N) ? *(const float4*)&x[(size_t)row * IN_DIM + k]
                        : make_float4(0.f, 0.f, 0.f, 0.f);
    }
#pragma unroll
    for (int kk = 0; kk < 4; kk++) {
      float4 w0 = *(float4*)&Ws[(k + kk) * OCOLS + c0];
      float4 w1 = *(float4*)&Ws[(k + kk) * OCOLS + c0 + 4];
#pragma unroll
      for (int r = 0; r < 4; r++) {
        float xk = (kk == 0) ? xr[r].x : (kk == 1) ? xr[r].y
                  : (kk == 2) ? xr[r].z : xr[r].w;
        acc[r][0] += xk * w0.x; acc[r][1] += xk * w0.y;
        acc[r][2] += xk * w0.z; acc[r][3] += xk * w0.w;
        acc[r][4] += xk * w1.x; acc[r][5] += xk * w1.y;
        acc[r][6] += xk * w1.z; acc[r][7] += xk * w1.w;
      }
    }
  }
#pragma unroll
  for (int r = 0; r < 4; r++) {
    int row = r0 + r;
    if (row < N) {
      *(float4*)&h[(size_t)row * OCOLS + c0]     = make_float4(acc[r][0], acc[r][1], acc[r][2], acc[r][3]);
      *(float4*)&h[(size_t)row * OCOLS + c0 + 4] = make_float4(acc[r][4], acc[r][5], acc[r][6], acc[r][7]);
    }
  }
}

// ------------- per-node attention scalars: alr[n] = {al0, al1, ar0, ar1} ---
__global__ __launch_bounds__(256) void alr_kernel(
    const float* __restrict__ h, const float* __restrict__ attn_l,
    const float* __restrict__ attn_r, float* __restrict__ alr, int N) {
  int gid = blockIdx.x * blockDim.x + threadIdx.x;
  int node = gid >> 6;
  int lane = threadIdx.x & 63;
  if (node >= N) return;
  float h0 = h[(size_t)node * OCOLS + lane];        // head 0, d = lane
  float h1 = h[(size_t)node * OCOLS + 64 + lane];   // head 1, d = lane
  float pl0 = h0 * attn_l[lane];
  float pl1 = h1 * attn_l[64 + lane];
  float pr0 = h0 * attn_r[lane];
  float pr1 = h1 * attn_r[64 + lane];
#pragma unroll
  for (int off = 32; off > 0; off >>= 1) {
    pl0 += __shfl_down(pl0, off);
    pl1 += __shfl_down(pl1, off);
    pr0 += __shfl_down(pr0, off);
    pr1 += __shfl_down(pr1, off);
  }
  if (lane == 0) {
    float4 v = make_float4(pl0, pl1, pr0, pr1);
    *(float4*)&alr[(size_t)node * 4] = v;
  }
}

__device__ inline void softmax_comb(float& m, float& s, float m2, float s2) {
  float M = fmaxf(m, m2);
  s = s * expf(m - M) + s2 * expf(m2 - M);
  m = M;
}

// ---- per-block online softmax (m,s) partials + dst histogram (fused) ----
// Does NOT materialize alpha; gather recomputes it from alr.
__global__ __launch_bounds__(256) void alpha_stats_kernel(
    const int* __restrict__ src, const int* __restrict__ dst,
    const float* __restrict__ alr, float* __restrict__ partials,
    int* __restrict__ cnt, int E) {
  float m0 = -1e30f, s0 = 0.f, m1 = -1e30f, s1 = 0.f;
  for (int e = blockIdx.x * 256 + threadIdx.x; e < E; e += gridDim.x * 256) {
    int sn = src[e], dn = dst[e];
    atomicAdd(&cnt[dn], 1);
    float4 as = *(const float4*)&alr[(size_t)sn * 4];
    float4 ad = *(const float4*)&alr[(size_t)dn * 4];
    float a0 = as.x + ad.z;
    float a1 = as.y + ad.w;
    a0 = (a0 > 0.f) ? a0 : 0.2f * a0;
    a1 = (a1 > 0.f) ? a1 : 0.2f * a1;
    {
      float M = fmaxf(m0, a0);
      s0 = s0 * expf(m0 - M) + expf(a0 - M);
      m0 = M;
    }
    {
      float M = fmaxf(m1, a1);
      s1 = s1 * expf(m1 - M) + expf(a1 - M);
      m1 = M;
    }
  }
#pragma unroll
  for (int off = 1; off < 64; off <<= 1) {
    float m0o = __shfl_xor(m0, off), s0o = __shfl_xor(s0, off);
    float m1o = __shfl_xor(m1, off), s1o = __shfl_xor(s1, off);
    softmax_comb(m0, s0, m0o, s0o);
    softmax_comb(m1, s1, m1o, s1o);
  }
  __shared__ float red[4][4];
  int wave = threadIdx.x >> 6;
  int lane = threadIdx.x & 63;
  if (lane == 0) {
    red[wave][0] = m0; red[wave][1] = s0; red[wave][2] = m1; red[wave][3] = s1;
  }
  __syncthreads();
  if (threadIdx.x == 0) {
    float M0 = red[0][0], S0 = red[0][1], M1 = red[0][2], S1 = red[0][3];
    for (int w = 1; w < 4; w++) {
      softmax_comb(M0, S0, red[w][0], red[w][1]);
      softmax_comb(M1, S1, red[w][2], red[w][3]);
    }
    float* p = &partials[(size_t)blockIdx.x * 4];
    p[0] = M0; p[1] = S0; p[2] = M1; p[3] = S1;
  }
}

// ---- combine NB_A partials -> stats {M0, 1/S0, M1, 1/S1} ----
__global__ __launch_bounds__(256) void reduce_kernel(
    const float* __restrict__ partials, float* __restrict__ stats) {
  float m0 = -1e30f, s0 = 0.f, m1 = -1e30f, s1 = 0.f;
  for (int i = threadIdx.x; i < NB_A; i += 256) {
    const float* p = &partials[(size_t)i * 4];
    softmax_comb(m0, s0, p[0], p[1]);
    softmax_comb(m1, s1, p[2], p[3]);
  }
#pragma unroll
  for (int off = 1; off < 64; off <<= 1) {
    float m0o = __shfl_xor(m0, off), s0o = __shfl_xor(s0, off);
    float m1o = __shfl_xor(m1, off), s1o = __shfl_xor(s1, off);
    softmax_comb(m0, s0, m0o, s0o);
    softmax_comb(m1, s1, m1o, s1o);
  }
  __shared__ float red[4][4];
  int wave = threadIdx.x >> 6;
  int lane = threadIdx.x & 63;
  if (lane == 0) {
    red[wave][0] = m0; red[wave][1] = s0; red[wave][2] = m1; red[wave][3] = s1;
  }
  __syncthreads();
  if (threadIdx.x == 0) {
    float M0 = red[0][0], S0 = red[0][1], M1 = red[0][2], S1 = red[0][3];
    for (int w = 1; w < 4; w++) {
      softmax_comb(M0, S0, red[w][0], red[w][1]);
      softmax_comb(M1, S1, red[w][2], red[w][3]);
    }
    stats[0] = M0; stats[1] = 1.f / S0;
    stats[2] = M1; stats[3] = 1.f / S1;
  }
}

// ---- exclusive scan cnt[0..N) -> off[0..N], cursor copy; 1 block x 1024 ----
__global__ __launch_bounds__(1024) void scan_kernel(
    const int* __restrict__ cnt, int* __restrict__ off,
    int* __restrict__ cursor, int N) {
  __shared__ int part[1024];
  int t = threadIdx.x;
  int chunk = (N + 1023) / 1024;
  int b = t * chunk;
  int e = min(b + chunk, N);
  int s = 0;
  for (int i = b; i < e; i++) s += cnt[i];
  part[t] = s;
  __syncthreads();
  for (int d = 1; d < 1024; d <<= 1) {
    int v = (t >= d) ? part[t - d] : 0;
    __syncthreads();
    part[t] += v;
    __syncthreads();
  }
  int run = (t == 0) ? 0 : part[t - 1];
  for (int i = b; i < e; i++) {
    int c = cnt[i];
    off[i] = run;
    cursor[i] = run;
    run += c;
  }
  if (t == 1023) off[N] = run;  // == E
}

// ---- counting-sort fill: edge_src grouped by dst ----
__global__ __launch_bounds__(256) void fill_kernel(
    const int* __restrict__ src, const int* __restrict__ dst,
    int* __restrict__ cursor, int* __restrict__ edge_src, int E) {
  int e = blockIdx.x * 256 + threadIdx.x;
  if (e >= E) return;
  int pos = atomicAdd(&cursor[dst[e]], 1);
  edge_src[pos] = src[e];
}

// ---- gather: one 64-lane wave per node, 2 edges in flight (2 x 32 lanes) ---
// lanes: sub = lane>>5 (edge slot), l = lane&31 (float4 column)
__global__ __launch_bounds__(256) void gather_kernel(
    const int* __restrict__ off, const int* __restrict__ edge_src,
    const float* __restrict__ alr, const float* __restrict__ stats,
    const float* __restrict__ h, float* __restrict__ out, int N) {
  int gid = blockIdx.x * 256 + threadIdx.x;
  int n = gid >> 6;
  if (n >= N) return;
  int lane = threadIdx.x & 63;
  int sub = lane >> 5;   // which of 2 concurrent edges
  int l = lane & 31;     // float4 index within the 128-col row
  int head = l >> 4;

  float4 ad = *(const float4*)&alr[(size_t)n * 4];
  float adv = head ? ad.w : ad.z;
  float M = stats[head * 2];
  float invS = stats[head * 2 + 1];

  int beg = off[n], end = off[n + 1];
  float4 acc = make_float4(0.f, 0.f, 0.f, 0.f);
  for (int i = beg + sub; i < end; i += 2) {
    int sn = edge_src[i];
    float4 as = *(const float4*)&alr[(size_t)sn * 4];
    float a = (head ? as.y : as.x) + adv;
    a = (a > 0.f) ? a : 0.2f * a;
    float w = expf(a - M) * invS;
    float4 hv = *(const float4*)&h[(size_t)sn * OCOLS + l * 4];
    acc.x += w * hv.x; acc.y += w * hv.y;
    acc.z += w * hv.z; acc.w += w * hv.w;
  }
  // combine the two edge slots (lane and lane^32 hold same column)
  acc.x += __shfl_xor(acc.x, 32);
  acc.y += __shfl_xor(acc.y, 32);
  acc.z += __shfl_xor(acc.z, 32);
  acc.w += __shfl_xor(acc.w, 32);
  if (sub == 0) {
    *(float4*)&out[(size_t)n * OCOLS + l * 4] = acc;
  }
}

extern "C" void kernel_launch(void* const* d_in, const int* in_sizes, int n_in,
                              void* d_out, int out_size, void* d_ws, size_t ws_size,
                              hipStream_t stream) {
  const float* x      = (const float*)d_in[0];
  const int*   edge   = (const int*)d_in[1];   // [2, E]
  const float* W      = (const float*)d_in[2];
  const float* attn_l = (const float*)d_in[3];
  const float* attn_r = (const float*)d_in[4];

  const int N = in_sizes[0] / IN_DIM;
  const int E = in_sizes[1] / 2;
  const int* src = edge;
  const int* dst = edge + E;
  float* out = (float*)d_out;

  // workspace layout (floats/ints, all 16B-aligned regions)
  float* h        = (float*)d_ws;                       // N*128 f
  float* alr      = h + (size_t)N * OCOLS;              // N*4 f
  float* partials = alr + (size_t)N * 4;                // NB_A*4 f
  float* stats    = partials + (size_t)NB_A * 4;        // 4 f
  int*   cnt      = (int*)(stats + 4);                  // N i
  int*   off      = cnt + N;                            // N+1 i
  int*   cursor   = off + N + 1;                        // N i
  int*   edge_src = cursor + N + ((N & 1) ? 1 : 0);     // E i (keep alignment)

  hipMemsetAsync(cnt, 0, (size_t)N * sizeof(int), stream);

  gemm_kernel<<<(N + 63) / 64, 256, 0, stream>>>(x, W, h, N);
  alr_kernel<<<((size_t)N * 64 + 255) / 256, 256, 0, stream>>>(h, attn_l, attn_r, alr, N);
  alpha_stats_kernel<<<NB_A, 256, 0, stream>>>(src, dst, alr, partials, cnt, E);
  reduce_kernel<<<1, 256, 0, stream>>>(partials, stats);
  scan_kernel<<<1, 1024, 0, stream>>>(cnt, off, cursor, N);
  fill_kernel<<<(E + 255) / 256, 256, 0, stream>>>(src, dst, cursor, edge_src, E);
  gather_kernel<<<((size_t)N * 64 + 255) / 256, 256, 0, stream>>>(
      off, edge_src, alr, stats, h, out, N);
}

// Round 3
// 591.207 us; speedup vs baseline: 5.0035x; 1.3412x over previous
//
#include <hip/hip_runtime.h>
#include <hip/hip_bf16.h>
#include <math.h>

#define IN_DIM   128
#define HEADS    2
#define OUT_DIM  64
#define OCOLS    128   // HEADS*OUT_DIM
#define NB_A     1024  // blocks for alpha/softmax partial pass
#define TILE     2048  // scan tile: 256 threads x 8 elems

// ---------------- GEMM: h[N,128] = x[N,128] @ W[128,128] ----------------
__global__ __launch_bounds__(256) void gemm_kernel(
    const float* __restrict__ x, const float* __restrict__ W,
    float* __restrict__ h, int N) {
  __shared__ float Ws[IN_DIM * OCOLS];  // 64 KB
  const int tid = threadIdx.x;
  for (int i = tid * 4; i < IN_DIM * OCOLS; i += 256 * 4) {
    *(float4*)&Ws[i] = *(const float4*)&W[i];
  }
  __syncthreads();

  const int rg = tid >> 4;       // 0..15
  const int cg = tid & 15;       // 0..15
  const int r0 = blockIdx.x * 64 + rg * 4;
  const int c0 = cg * 8;

  float acc[4][8];
#pragma unroll
  for (int r = 0; r < 4; r++)
#pragma unroll
    for (int c = 0; c < 8; c++) acc[r][c] = 0.f;

  for (int k = 0; k < IN_DIM; k += 4) {
    float4 xr[4];
#pragma unroll
    for (int r = 0; r < 4; r++) {
      int row = r0 + r;
      xr[r] = (row < N) ? *(const float4*)&x[(size_t)row * IN_DIM + k]
                        : make_float4(0.f, 0.f, 0.f, 0.f);
    }
#pragma unroll
    for (int kk = 0; kk < 4; kk++) {
      float4 w0 = *(float4*)&Ws[(k + kk) * OCOLS + c0];
      float4 w1 = *(float4*)&Ws[(k + kk) * OCOLS + c0 + 4];
#pragma unroll
      for (int r = 0; r < 4; r++) {
        float xk = (kk == 0) ? xr[r].x : (kk == 1) ? xr[r].y
                  : (kk == 2) ? xr[r].z : xr[r].w;
        acc[r][0] += xk * w0.x; acc[r][1] += xk * w0.y;
        acc[r][2] += xk * w0.z; acc[r][3] += xk * w0.w;
        acc[r][4] += xk * w1.x; acc[r][5] += xk * w1.y;
        acc[r][6] += xk * w1.z; acc[r][7] += xk * w1.w;
      }
    }
  }
#pragma unroll
  for (int r = 0; r < 4; r++) {
    int row = r0 + r;
    if (row < N) {
      *(float4*)&h[(size_t)row * OCOLS + c0]     = make_float4(acc[r][0], acc[r][1], acc[r][2], acc[r][3]);
      *(float4*)&h[(size_t)row * OCOLS + c0 + 4] = make_float4(acc[r][4], acc[r][5], acc[r][6], acc[r][7]);
    }
  }
}

// ------------- per-node attention scalars: alr[n] = {al0, al1, ar0, ar1} ---
__global__ __launch_bounds__(256) void alr_kernel(
    const float* __restrict__ h, const float* __restrict__ attn_l,
    const float* __restrict__ attn_r, float* __restrict__ alr, int N) {
  int gid = blockIdx.x * blockDim.x + threadIdx.x;
  int node = gid >> 6;
  int lane = threadIdx.x & 63;
  if (node >= N) return;
  float h0 = h[(size_t)node * OCOLS + lane];        // head 0, d = lane
  float h1 = h[(size_t)node * OCOLS + 64 + lane];   // head 1, d = lane
  float pl0 = h0 * attn_l[lane];
  float pl1 = h1 * attn_l[64 + lane];
  float pr0 = h0 * attn_r[lane];
  float pr1 = h1 * attn_r[64 + lane];
#pragma unroll
  for (int off = 32; off > 0; off >>= 1) {
    pl0 += __shfl_down(pl0, off);
    pl1 += __shfl_down(pl1, off);
    pr0 += __shfl_down(pr0, off);
    pr1 += __shfl_down(pr1, off);
  }
  if (lane == 0) {
    float4 v = make_float4(pl0, pl1, pr0, pr1);
    *(float4*)&alr[(size_t)node * 4] = v;
  }
}

__device__ inline void softmax_comb(float& m, float& s, float m2, float s2) {
  float M = fmaxf(m, m2);
  s = s * expf(m - M) + s2 * expf(m2 - M);
  m = M;
}

// ---- per-block online softmax (m,s) partials + dst histogram (fused) ----
__global__ __launch_bounds__(256) void alpha_stats_kernel(
    const int* __restrict__ src, const int* __restrict__ dst,
    const float* __restrict__ alr, float* __restrict__ partials,
    int* __restrict__ cnt, int E) {
  float m0 = -1e30f, s0 = 0.f, m1 = -1e30f, s1 = 0.f;
  for (int e = blockIdx.x * 256 + threadIdx.x; e < E; e += gridDim.x * 256) {
    int sn = src[e], dn = dst[e];
    atomicAdd(&cnt[dn], 1);
    float4 as = *(const float4*)&alr[(size_t)sn * 4];
    float4 ad = *(const float4*)&alr[(size_t)dn * 4];
    float a0 = as.x + ad.z;
    float a1 = as.y + ad.w;
    a0 = (a0 > 0.f) ? a0 : 0.2f * a0;
    a1 = (a1 > 0.f) ? a1 : 0.2f * a1;
    {
      float M = fmaxf(m0, a0);
      s0 = s0 * expf(m0 - M) + expf(a0 - M);
      m0 = M;
    }
    {
      float M = fmaxf(m1, a1);
      s1 = s1 * expf(m1 - M) + expf(a1 - M);
      m1 = M;
    }
  }
#pragma unroll
  for (int off = 1; off < 64; off <<= 1) {
    float m0o = __shfl_xor(m0, off), s0o = __shfl_xor(s0, off);
    float m1o = __shfl_xor(m1, off), s1o = __shfl_xor(s1, off);
    softmax_comb(m0, s0, m0o, s0o);
    softmax_comb(m1, s1, m1o, s1o);
  }
  __shared__ float red[4][4];
  int wave = threadIdx.x >> 6;
  int lane = threadIdx.x & 63;
  if (lane == 0) {
    red[wave][0] = m0; red[wave][1] = s0; red[wave][2] = m1; red[wave][3] = s1;
  }
  __syncthreads();
  if (threadIdx.x == 0) {
    float M0 = red[0][0], S0 = red[0][1], M1 = red[0][2], S1 = red[0][3];
    for (int w = 1; w < 4; w++) {
      softmax_comb(M0, S0, red[w][0], red[w][1]);
      softmax_comb(M1, S1, red[w][2], red[w][3]);
    }
    float* p = &partials[(size_t)blockIdx.x * 4];
    p[0] = M0; p[1] = S0; p[2] = M1; p[3] = S1;
  }
}

// ---- combine NB_A partials -> stats {M0, 1/S0, M1, 1/S1} ----
__global__ __launch_bounds__(256) void reduce_kernel(
    const float* __restrict__ partials, float* __restrict__ stats) {
  float m0 = -1e30f, s0 = 0.f, m1 = -1e30f, s1 = 0.f;
  for (int i = threadIdx.x; i < NB_A; i += 256) {
    const float* p = &partials[(size_t)i * 4];
    softmax_comb(m0, s0, p[0], p[1]);
    softmax_comb(m1, s1, p[2], p[3]);
  }
#pragma unroll
  for (int off = 1; off < 64; off <<= 1) {
    float m0o = __shfl_xor(m0, off), s0o = __shfl_xor(s0, off);
    float m1o = __shfl_xor(m1, off), s1o = __shfl_xor(s1, off);
    softmax_comb(m0, s0, m0o, s0o);
    softmax_comb(m1, s1, m1o, s1o);
  }
  __shared__ float red[4][4];
  int wave = threadIdx.x >> 6;
  int lane = threadIdx.x & 63;
  if (lane == 0) {
    red[wave][0] = m0; red[wave][1] = s0; red[wave][2] = m1; red[wave][3] = s1;
  }
  __syncthreads();
  if (threadIdx.x == 0) {
    float M0 = red[0][0], S0 = red[0][1], M1 = red[0][2], S1 = red[0][3];
    for (int w = 1; w < 4; w++) {
      softmax_comb(M0, S0, red[w][0], red[w][1]);
      softmax_comb(M1, S1, red[w][2], red[w][3]);
    }
    stats[0] = M0; stats[1] = 1.f / S0;
    stats[2] = M1; stats[3] = 1.f / S1;
  }
}

// ---- hierarchical scan pass 1: per-block sums of cnt tiles ----
__global__ __launch_bounds__(256) void scan_blocksum_kernel(
    const int* __restrict__ cnt, int* __restrict__ blk, int N) {
  int base = blockIdx.x * TILE + threadIdx.x * 8;
  int s = 0;
#pragma unroll
  for (int j = 0; j < 8; j++) {
    int i = base + j;
    if (i < N) s += cnt[i];
  }
#pragma unroll
  for (int off = 1; off < 64; off <<= 1) s += __shfl_xor(s, off);
  __shared__ int ws[4];
  if ((threadIdx.x & 63) == 0) ws[threadIdx.x >> 6] = s;
  __syncthreads();
  if (threadIdx.x == 0) blk[blockIdx.x] = ws[0] + ws[1] + ws[2] + ws[3];
}

// ---- pass 2: exclusive scan of block sums (nb <= 1024); writes off[N] ----
__global__ __launch_bounds__(1024) void scan_blk_kernel(
    int* __restrict__ blk, int* __restrict__ off, int nb, int N) {
  __shared__ int part[1024];
  int t = threadIdx.x;
  int v = (t < nb) ? blk[t] : 0;
  part[t] = v;
  __syncthreads();
  for (int d = 1; d < 1024; d <<= 1) {
    int x = (t >= d) ? part[t - d] : 0;
    __syncthreads();
    part[t] += x;
    __syncthreads();
  }
  if (t < nb) blk[t] = part[t] - v;       // exclusive prefix
  if (t == 1023) off[N] = part[1023];     // total == E
}

// ---- pass 3: write off/cursor with block prefix + local scan ----
__global__ __launch_bounds__(256) void scan_write_kernel(
    const int* __restrict__ cnt, const int* __restrict__ blk,
    int* __restrict__ off, int* __restrict__ cursor, int N) {
  int t = threadIdx.x;
  int base = blockIdx.x * TILE + t * 8;
  int v[8];
  int s = 0;
#pragma unroll
  for (int j = 0; j < 8; j++) {
    int i = base + j;
    v[j] = (i < N) ? cnt[i] : 0;
    s += v[j];
  }
  __shared__ int part[256];
  part[t] = s;
  __syncthreads();
  for (int d = 1; d < 256; d <<= 1) {
    int x = (t >= d) ? part[t - d] : 0;
    __syncthreads();
    part[t] += x;
    __syncthreads();
  }
  int run = blk[blockIdx.x] + ((t == 0) ? 0 : part[t - 1]);
#pragma unroll
  for (int j = 0; j < 8; j++) {
    int i = base + j;
    if (i < N) {
      off[i] = run;
      cursor[i] = run;
      run += v[j];
    }
  }
}

// ---- counting-sort fill: edge_src grouped by dst ----
__global__ __launch_bounds__(256) void fill_kernel(
    const int* __restrict__ src, const int* __restrict__ dst,
    int* __restrict__ cursor, int* __restrict__ edge_src, int E) {
  int e = blockIdx.x * 256 + threadIdx.x;
  if (e >= E) return;
  int pos = atomicAdd(&cursor[dst[e]], 1);
  edge_src[pos] = src[e];
}

// ---- gather: one 64-lane wave per node, 2 edges in flight (2 x 32 lanes) ---
__global__ __launch_bounds__(256) void gather_kernel(
    const int* __restrict__ off, const int* __restrict__ edge_src,
    const float* __restrict__ alr, const float* __restrict__ stats,
    const float* __restrict__ h, float* __restrict__ out, int N) {
  int gid = blockIdx.x * 256 + threadIdx.x;
  int n = gid >> 6;
  if (n >= N) return;
  int lane = threadIdx.x & 63;
  int sub = lane >> 5;   // which of 2 concurrent edges
  int l = lane & 31;     // float4 index within the 128-col row
  int head = l >> 4;

  float4 ad = *(const float4*)&alr[(size_t)n * 4];
  float adv = head ? ad.w : ad.z;
  float M = stats[head * 2];
  float invS = stats[head * 2 + 1];

  int beg = off[n], end = off[n + 1];
  float4 acc = make_float4(0.f, 0.f, 0.f, 0.f);
  for (int i = beg + sub; i < end; i += 2) {
    int sn = edge_src[i];
    float4 as = *(const float4*)&alr[(size_t)sn * 4];
    float a = (head ? as.y : as.x) + adv;
    a = (a > 0.f) ? a : 0.2f * a;
    float w = expf(a - M) * invS;
    float4 hv = *(const float4*)&h[(size_t)sn * OCOLS + l * 4];
    acc.x += w * hv.x; acc.y += w * hv.y;
    acc.z += w * hv.z; acc.w += w * hv.w;
  }
  acc.x += __shfl_xor(acc.x, 32);
  acc.y += __shfl_xor(acc.y, 32);
  acc.z += __shfl_xor(acc.z, 32);
  acc.w += __shfl_xor(acc.w, 32);
  if (sub == 0) {
    *(float4*)&out[(size_t)n * OCOLS + l * 4] = acc;
  }
}

extern "C" void kernel_launch(void* const* d_in, const int* in_sizes, int n_in,
                              void* d_out, int out_size, void* d_ws, size_t ws_size,
                              hipStream_t stream) {
  const float* x      = (const float*)d_in[0];
  const int*   edge   = (const int*)d_in[1];   // [2, E]
  const float* W      = (const float*)d_in[2];
  const float* attn_l = (const float*)d_in[3];
  const float* attn_r = (const float*)d_in[4];

  const int N = in_sizes[0] / IN_DIM;
  const int E = in_sizes[1] / 2;
  const int* src = edge;
  const int* dst = edge + E;
  float* out = (float*)d_out;

  // workspace layout
  float* h        = (float*)d_ws;                       // N*128 f
  float* alr      = h + (size_t)N * OCOLS;              // N*4 f
  float* partials = alr + (size_t)N * 4;                // NB_A*4 f
  float* stats    = partials + (size_t)NB_A * 4;        // 4 f
  int*   cnt      = (int*)(stats + 4);                  // N i
  int*   off      = cnt + N;                            // N+1 i
  int*   cursor   = off + N + 1;                        // N i
  int*   blk      = cursor + N;                         // 1024 i
  int*   edge_src = blk + 1024;                         // E i

  const int nb = (N + TILE - 1) / TILE;

  hipMemsetAsync(cnt, 0, (size_t)N * sizeof(int), stream);

  gemm_kernel<<<(N + 63) / 64, 256, 0, stream>>>(x, W, h, N);
  alr_kernel<<<((size_t)N * 64 + 255) / 256, 256, 0, stream>>>(h, attn_l, attn_r, alr, N);
  alpha_stats_kernel<<<NB_A, 256, 0, stream>>>(src, dst, alr, partials, cnt, E);
  reduce_kernel<<<1, 256, 0, stream>>>(partials, stats);
  scan_blocksum_kernel<<<nb, 256, 0, stream>>>(cnt, blk, N);
  scan_blk_kernel<<<1, 1024, 0, stream>>>(blk, off, nb, N);
  scan_write_kernel<<<nb, 256, 0, stream>>>(cnt, blk, off, cursor, N);
  fill_kernel<<<(E + 255) / 256, 256, 0, stream>>>(src, dst, cursor, edge_src, E);
  gather_kernel<<<((size_t)N * 64 + 255) / 256, 256, 0, stream>>>(
      off, edge_src, alr, stats, h, out, N);
}

// Round 4
// 468.307 us; speedup vs baseline: 6.3166x; 1.2624x over previous
//
#include <hip/hip_runtime.h>
#include <hip/hip_fp16.h>
#include <math.h>

#define IN_DIM   128
#define HEADS    2
#define OUT_DIM  64
#define OCOLS    128   // HEADS*OUT_DIM
#define NB_A     1024  // blocks for alpha/softmax partial pass
#define TILE     2048  // scan tile: 256 threads x 8 elems

typedef __attribute__((ext_vector_type(4))) _Float16 half4v;  // 8 B
typedef __attribute__((ext_vector_type(8))) _Float16 half8v;  // 16 B

// ------- GEMM + fused epilogue: h16 = fp16(x@W), alr[n] = {al0,al1,ar0,ar1} -
// Block: 256 thr = 16 rowgroups x 16 colgroups; tile 64 rows x 128 cols.
// W staged in LDS in two 32KB k-halves (5 blocks/CU vs 2 at 64KB).
// Columns per thread: c0=cg*4 (head0) and 64+c0 (head1) -> <=2-way LDS
// bank aliasing (free), vs 4-way at the old cg*8 mapping.
__global__ __launch_bounds__(256) void gemm_kernel(
    const float* __restrict__ x, const float* __restrict__ W,
    const float* __restrict__ attn_l, const float* __restrict__ attn_r,
    _Float16* __restrict__ h16, float* __restrict__ alr, int N) {
  __shared__ float Ws[64 * OCOLS];  // 32 KB
  const int tid = threadIdx.x;
  const int rg = tid >> 4;       // 0..15
  const int cg = tid & 15;       // 0..15
  const int r0 = blockIdx.x * 64 + rg * 4;
  const int c0 = cg * 4;

  float acc[4][8];
#pragma unroll
  for (int r = 0; r < 4; r++)
#pragma unroll
    for (int c = 0; c < 8; c++) acc[r][c] = 0.f;

  for (int half = 0; half < 2; half++) {
    if (half) __syncthreads();   // protect Ws reuse
    for (int i = tid * 4; i < 64 * OCOLS; i += 256 * 4) {
      *(float4*)&Ws[i] = *(const float4*)&W[half * 64 * OCOLS + i];
    }
    __syncthreads();
    for (int k = 0; k < 64; k += 4) {
      float4 xr[4];
#pragma unroll
      for (int r = 0; r < 4; r++) {
        int row = r0 + r;
        xr[r] = (row < N)
            ? *(const float4*)&x[(size_t)row * IN_DIM + half * 64 + k]
            : make_float4(0.f, 0.f, 0.f, 0.f);
      }
#pragma unroll
      for (int kk = 0; kk < 4; kk++) {
        float4 w0 = *(float4*)&Ws[(k + kk) * OCOLS + c0];
        float4 w1 = *(float4*)&Ws[(k + kk) * OCOLS + 64 + c0];
#pragma unroll
        for (int r = 0; r < 4; r++) {
          float xk = (kk == 0) ? xr[r].x : (kk == 1) ? xr[r].y
                    : (kk == 2) ? xr[r].z : xr[r].w;
          acc[r][0] += xk * w0.x; acc[r][1] += xk * w0.y;
          acc[r][2] += xk * w0.z; acc[r][3] += xk * w0.w;
          acc[r][4] += xk * w1.x; acc[r][5] += xk * w1.y;
          acc[r][6] += xk * w1.z; acc[r][7] += xk * w1.w;
        }
      }
    }
  }

  // epilogue: fp16 store of h + per-row attention scalars (16-lane reduce)
  float4 Al0 = *(const float4*)&attn_l[c0];
  float4 Al1 = *(const float4*)&attn_l[64 + c0];
  float4 Ar0 = *(const float4*)&attn_r[c0];
  float4 Ar1 = *(const float4*)&attn_r[64 + c0];
#pragma unroll
  for (int r = 0; r < 4; r++) {
    int row = r0 + r;
    if (row < N) {
      half4v v0, v1;
#pragma unroll
      for (int j = 0; j < 4; j++) {
        v0[j] = (_Float16)acc[r][j];
        v1[j] = (_Float16)acc[r][4 + j];
      }
      *(half4v*)&h16[(size_t)row * OCOLS + c0]      = v0;
      *(half4v*)&h16[(size_t)row * OCOLS + 64 + c0] = v1;
    }
    float al0 = acc[r][0]*Al0.x + acc[r][1]*Al0.y + acc[r][2]*Al0.z + acc[r][3]*Al0.w;
    float al1 = acc[r][4]*Al1.x + acc[r][5]*Al1.y + acc[r][6]*Al1.z + acc[r][7]*Al1.w;
    float ar0 = acc[r][0]*Ar0.x + acc[r][1]*Ar0.y + acc[r][2]*Ar0.z + acc[r][3]*Ar0.w;
    float ar1 = acc[r][4]*Ar1.x + acc[r][5]*Ar1.y + acc[r][6]*Ar1.z + acc[r][7]*Ar1.w;
#pragma unroll
    for (int off = 1; off < 16; off <<= 1) {
      al0 += __shfl_xor(al0, off);
      al1 += __shfl_xor(al1, off);
      ar0 += __shfl_xor(ar0, off);
      ar1 += __shfl_xor(ar1, off);
    }
    if (cg == 0 && row < N) {
      *(float4*)&alr[(size_t)row * 4] = make_float4(al0, al1, ar0, ar1);
    }
  }
}

__device__ inline void softmax_comb(float& m, float& s, float m2, float s2) {
  float M = fmaxf(m, m2);
  s = s * expf(m - M) + s2 * expf(m2 - M);
  m = M;
}

// ---- per-block online softmax (m,s) partials + dst histogram (fused) ----
__global__ __launch_bounds__(256) void alpha_stats_kernel(
    const int* __restrict__ src, const int* __restrict__ dst,
    const float* __restrict__ alr, float* __restrict__ partials,
    int* __restrict__ cnt, int E) {
  float m0 = -1e30f, s0 = 0.f, m1 = -1e30f, s1 = 0.f;
  for (int e = blockIdx.x * 256 + threadIdx.x; e < E; e += gridDim.x * 256) {
    int sn = src[e], dn = dst[e];
    atomicAdd(&cnt[dn], 1);
    float4 as = *(const float4*)&alr[(size_t)sn * 4];
    float4 ad = *(const float4*)&alr[(size_t)dn * 4];
    float a0 = as.x + ad.z;
    float a1 = as.y + ad.w;
    a0 = (a0 > 0.f) ? a0 : 0.2f * a0;
    a1 = (a1 > 0.f) ? a1 : 0.2f * a1;
    {
      float M = fmaxf(m0, a0);
      s0 = s0 * expf(m0 - M) + expf(a0 - M);
      m0 = M;
    }
    {
      float M = fmaxf(m1, a1);
      s1 = s1 * expf(m1 - M) + expf(a1 - M);
      m1 = M;
    }
  }
#pragma unroll
  for (int off = 1; off < 64; off <<= 1) {
    float m0o = __shfl_xor(m0, off), s0o = __shfl_xor(s0, off);
    float m1o = __shfl_xor(m1, off), s1o = __shfl_xor(s1, off);
    softmax_comb(m0, s0, m0o, s0o);
    softmax_comb(m1, s1, m1o, s1o);
  }
  __shared__ float red[4][4];
  int wave = threadIdx.x >> 6;
  int lane = threadIdx.x & 63;
  if (lane == 0) {
    red[wave][0] = m0; red[wave][1] = s0; red[wave][2] = m1; red[wave][3] = s1;
  }
  __syncthreads();
  if (threadIdx.x == 0) {
    float M0 = red[0][0], S0 = red[0][1], M1 = red[0][2], S1 = red[0][3];
    for (int w = 1; w < 4; w++) {
      softmax_comb(M0, S0, red[w][0], red[w][1]);
      softmax_comb(M1, S1, red[w][2], red[w][3]);
    }
    float* p = &partials[(size_t)blockIdx.x * 4];
    p[0] = M0; p[1] = S0; p[2] = M1; p[3] = S1;
  }
}

// ---- combine NB_A partials -> stats {M0, 1/S0, M1, 1/S1} ----
__global__ __launch_bounds__(256) void reduce_kernel(
    const float* __restrict__ partials, float* __restrict__ stats) {
  float m0 = -1e30f, s0 = 0.f, m1 = -1e30f, s1 = 0.f;
  for (int i = threadIdx.x; i < NB_A; i += 256) {
    const float* p = &partials[(size_t)i * 4];
    softmax_comb(m0, s0, p[0], p[1]);
    softmax_comb(m1, s1, p[2], p[3]);
  }
#pragma unroll
  for (int off = 1; off < 64; off <<= 1) {
    float m0o = __shfl_xor(m0, off), s0o = __shfl_xor(s0, off);
    float m1o = __shfl_xor(m1, off), s1o = __shfl_xor(s1, off);
    softmax_comb(m0, s0, m0o, s0o);
    softmax_comb(m1, s1, m1o, s1o);
  }
  __shared__ float red[4][4];
  int wave = threadIdx.x >> 6;
  int lane = threadIdx.x & 63;
  if (lane == 0) {
    red[wave][0] = m0; red[wave][1] = s0; red[wave][2] = m1; red[wave][3] = s1;
  }
  __syncthreads();
  if (threadIdx.x == 0) {
    float M0 = red[0][0], S0 = red[0][1], M1 = red[0][2], S1 = red[0][3];
    for (int w = 1; w < 4; w++) {
      softmax_comb(M0, S0, red[w][0], red[w][1]);
      softmax_comb(M1, S1, red[w][2], red[w][3]);
    }
    stats[0] = M0; stats[1] = 1.f / S0;
    stats[2] = M1; stats[3] = 1.f / S1;
  }
}

// ---- hierarchical scan pass 1: per-block sums of cnt tiles ----
__global__ __launch_bounds__(256) void scan_blocksum_kernel(
    const int* __restrict__ cnt, int* __restrict__ blk, int N) {
  int base = blockIdx.x * TILE + threadIdx.x * 8;
  int s = 0;
#pragma unroll
  for (int j = 0; j < 8; j++) {
    int i = base + j;
    if (i < N) s += cnt[i];
  }
#pragma unroll
  for (int off = 1; off < 64; off <<= 1) s += __shfl_xor(s, off);
  __shared__ int ws[4];
  if ((threadIdx.x & 63) == 0) ws[threadIdx.x >> 6] = s;
  __syncthreads();
  if (threadIdx.x == 0) blk[blockIdx.x] = ws[0] + ws[1] + ws[2] + ws[3];
}

// ---- pass 2: exclusive scan of block sums (nb <= 1024); writes off[N] ----
__global__ __launch_bounds__(1024) void scan_blk_kernel(
    int* __restrict__ blk, int* __restrict__ off, int nb, int N) {
  __shared__ int part[1024];
  int t = threadIdx.x;
  int v = (t < nb) ? blk[t] : 0;
  part[t] = v;
  __syncthreads();
  for (int d = 1; d < 1024; d <<= 1) {
    int x = (t >= d) ? part[t - d] : 0;
    __syncthreads();
    part[t] += x;
    __syncthreads();
  }
  if (t < nb) blk[t] = part[t] - v;       // exclusive prefix
  if (t == 1023) off[N] = part[1023];     // total == E
}

// ---- pass 3: write off/cursor with block prefix + local scan ----
__global__ __launch_bounds__(256) void scan_write_kernel(
    const int* __restrict__ cnt, const int* __restrict__ blk,
    int* __restrict__ off, int* __restrict__ cursor, int N) {
  int t = threadIdx.x;
  int base = blockIdx.x * TILE + t * 8;
  int v[8];
  int s = 0;
#pragma unroll
  for (int j = 0; j < 8; j++) {
    int i = base + j;
    v[j] = (i < N) ? cnt[i] : 0;
    s += v[j];
  }
  __shared__ int part[256];
  part[t] = s;
  __syncthreads();
  for (int d = 1; d < 256; d <<= 1) {
    int x = (t >= d) ? part[t - d] : 0;
    __syncthreads();
    part[t] += x;
    __syncthreads();
  }
  int run = blk[blockIdx.x] + ((t == 0) ? 0 : part[t - 1]);
#pragma unroll
  for (int j = 0; j < 8; j++) {
    int i = base + j;
    if (i < N) {
      off[i] = run;
      cursor[i] = run;
      run += v[j];
    }
  }
}

// ---- counting-sort fill: edge_src grouped by dst ----
__global__ __launch_bounds__(256) void fill_kernel(
    const int* __restrict__ src, const int* __restrict__ dst,
    int* __restrict__ cursor, int* __restrict__ edge_src, int E) {
  int e = blockIdx.x * 256 + threadIdx.x;
  if (e >= E) return;
  int pos = atomicAdd(&cursor[dst[e]], 1);
  edge_src[pos] = src[e];
}

// ---- gather: one wave per node, 4 edges in flight (4 x 16 lanes), fp16 h ---
// lanes: sub = lane>>4 (edge slot), l = lane&15 (8-half column group)
__global__ __launch_bounds__(256) void gather_kernel(
    const int* __restrict__ off, const int* __restrict__ edge_src,
    const float* __restrict__ alr, const float* __restrict__ stats,
    const _Float16* __restrict__ h16, float* __restrict__ out, int N) {
  int gid = blockIdx.x * 256 + threadIdx.x;
  int n = gid >> 6;
  if (n >= N) return;
  int lane = threadIdx.x & 63;
  int sub = lane >> 4;   // which of 4 concurrent edges
  int l = lane & 15;     // covers halves [l*8, l*8+8)
  int head = l >> 3;

  float4 ad = *(const float4*)&alr[(size_t)n * 4];
  float adv = head ? ad.w : ad.z;
  float M = stats[head * 2];
  float invS = stats[head * 2 + 1];

  int beg = off[n], end = off[n + 1];
  float acc[8] = {0.f, 0.f, 0.f, 0.f, 0.f, 0.f, 0.f, 0.f};
  for (int i = beg + sub; i < end; i += 4) {
    int sn = edge_src[i];
    float4 as = *(const float4*)&alr[(size_t)sn * 4];
    float a = (head ? as.y : as.x) + adv;
    a = (a > 0.f) ? a : 0.2f * a;
    float w = expf(a - M) * invS;
    half8v hv = *(const half8v*)&h16[(size_t)sn * OCOLS + l * 8];
#pragma unroll
    for (int j = 0; j < 8; j++) acc[j] += w * (float)hv[j];
  }
#pragma unroll
  for (int j = 0; j < 8; j++) {
    acc[j] += __shfl_xor(acc[j], 16);
    acc[j] += __shfl_xor(acc[j], 32);
  }
  if (sub == 0) {
    *(float4*)&out[(size_t)n * OCOLS + l * 8]     = make_float4(acc[0], acc[1], acc[2], acc[3]);
    *(float4*)&out[(size_t)n * OCOLS + l * 8 + 4] = make_float4(acc[4], acc[5], acc[6], acc[7]);
  }
}

extern "C" void kernel_launch(void* const* d_in, const int* in_sizes, int n_in,
                              void* d_out, int out_size, void* d_ws, size_t ws_size,
                              hipStream_t stream) {
  const float* x      = (const float*)d_in[0];
  const int*   edge   = (const int*)d_in[1];   // [2, E]
  const float* W      = (const float*)d_in[2];
  const float* attn_l = (const float*)d_in[3];
  const float* attn_r = (const float*)d_in[4];

  const int N = in_sizes[0] / IN_DIM;
  const int E = in_sizes[1] / 2;
  const int* src = edge;
  const int* dst = edge + E;
  float* out = (float*)d_out;

  // workspace layout
  _Float16* h16      = (_Float16*)d_ws;                 // N*128 h  (25.6 MB)
  float*    alr      = (float*)(h16 + (size_t)N * OCOLS);  // N*4 f
  float*    partials = alr + (size_t)N * 4;             // NB_A*4 f
  float*    stats    = partials + (size_t)NB_A * 4;     // 4 f
  int*      cnt      = (int*)(stats + 4);               // N i
  int*      off      = cnt + N;                         // N+1 i
  int*      cursor   = off + N + 1;                     // N i
  int*      blk      = cursor + N;                      // 1024 i
  int*      edge_src = blk + 1024;                      // E i

  const int nb = (N + TILE - 1) / TILE;

  hipMemsetAsync(cnt, 0, (size_t)N * sizeof(int), stream);

  gemm_kernel<<<(N + 63) / 64, 256, 0, stream>>>(x, W, attn_l, attn_r, h16, alr, N);
  alpha_stats_kernel<<<NB_A, 256, 0, stream>>>(src, dst, alr, partials, cnt, E);
  reduce_kernel<<<1, 256, 0, stream>>>(partials, stats);
  scan_blocksum_kernel<<<nb, 256, 0, stream>>>(cnt, blk, N);
  scan_blk_kernel<<<1, 1024, 0, stream>>>(blk, off, nb, N);
  scan_write_kernel<<<nb, 256, 0, stream>>>(cnt, blk, off, cursor, N);
  fill_kernel<<<(E + 255) / 256, 256, 0, stream>>>(src, dst, cursor, edge_src, E);
  gather_kernel<<<((size_t)N * 64 + 255) / 256, 256, 0, stream>>>(
      off, edge_src, alr, stats, h16, out, N);
}

// Round 5
// 359.908 us; speedup vs baseline: 8.2191x; 1.3012x over previous
//
#include <hip/hip_runtime.h>
#include <hip/hip_fp16.h>
#include <math.h>

#define IN_DIM   128
#define HEADS    2
#define OUT_DIM  64
#define OCOLS    128   // HEADS*OUT_DIM
#define NB_A     1024  // blocks for alpha/softmax partial pass
#define BSHIFT   8     // 256 nodes per bucket
#define MAXB     512   // max buckets (N<=131072)
#define CAP      6144  // bucket_csr LDS buffer capacity (edges); mean 4096
#define HISTB    128   // blocks for hist kernel
#define PARTB    128   // blocks for partition kernel

typedef __attribute__((ext_vector_type(4))) _Float16 half4v;  // 8 B
typedef __attribute__((ext_vector_type(8))) _Float16 half8v;  // 16 B

// ------- GEMM + fused epilogue: h16 = fp16(x@W), alr[n] = {al0,al1,ar0,ar1} -
__global__ __launch_bounds__(256) void gemm_kernel(
    const float* __restrict__ x, const float* __restrict__ W,
    const float* __restrict__ attn_l, const float* __restrict__ attn_r,
    _Float16* __restrict__ h16, float* __restrict__ alr, int N) {
  __shared__ float Ws[64 * OCOLS];  // 32 KB
  const int tid = threadIdx.x;
  const int rg = tid >> 4;       // 0..15
  const int cg = tid & 15;       // 0..15
  const int r0 = blockIdx.x * 64 + rg * 4;
  const int c0 = cg * 4;

  float acc[4][8];
#pragma unroll
  for (int r = 0; r < 4; r++)
#pragma unroll
    for (int c = 0; c < 8; c++) acc[r][c] = 0.f;

  for (int half = 0; half < 2; half++) {
    if (half) __syncthreads();   // protect Ws reuse
    for (int i = tid * 4; i < 64 * OCOLS; i += 256 * 4) {
      *(float4*)&Ws[i] = *(const float4*)&W[half * 64 * OCOLS + i];
    }
    __syncthreads();
    for (int k = 0; k < 64; k += 4) {
      float4 xr[4];
#pragma unroll
      for (int r = 0; r < 4; r++) {
        int row = r0 + r;
        xr[r] = (row < N)
            ? *(const float4*)&x[(size_t)row * IN_DIM + half * 64 + k]
            : make_float4(0.f, 0.f, 0.f, 0.f);
      }
#pragma unroll
      for (int kk = 0; kk < 4; kk++) {
        float4 w0 = *(float4*)&Ws[(k + kk) * OCOLS + c0];
        float4 w1 = *(float4*)&Ws[(k + kk) * OCOLS + 64 + c0];
#pragma unroll
        for (int r = 0; r < 4; r++) {
          float xk = (kk == 0) ? xr[r].x : (kk == 1) ? xr[r].y
                    : (kk == 2) ? xr[r].z : xr[r].w;
          acc[r][0] += xk * w0.x; acc[r][1] += xk * w0.y;
          acc[r][2] += xk * w0.z; acc[r][3] += xk * w0.w;
          acc[r][4] += xk * w1.x; acc[r][5] += xk * w1.y;
          acc[r][6] += xk * w1.z; acc[r][7] += xk * w1.w;
        }
      }
    }
  }

  // epilogue: fp16 store of h + per-row attention scalars (16-lane reduce)
  float4 Al0 = *(const float4*)&attn_l[c0];
  float4 Al1 = *(const float4*)&attn_l[64 + c0];
  float4 Ar0 = *(const float4*)&attn_r[c0];
  float4 Ar1 = *(const float4*)&attn_r[64 + c0];
#pragma unroll
  for (int r = 0; r < 4; r++) {
    int row = r0 + r;
    if (row < N) {
      half4v v0, v1;
#pragma unroll
      for (int j = 0; j < 4; j++) {
        v0[j] = (_Float16)acc[r][j];
        v1[j] = (_Float16)acc[r][4 + j];
      }
      *(half4v*)&h16[(size_t)row * OCOLS + c0]      = v0;
      *(half4v*)&h16[(size_t)row * OCOLS + 64 + c0] = v1;
    }
    float al0 = acc[r][0]*Al0.x + acc[r][1]*Al0.y + acc[r][2]*Al0.z + acc[r][3]*Al0.w;
    float al1 = acc[r][4]*Al1.x + acc[r][5]*Al1.y + acc[r][6]*Al1.z + acc[r][7]*Al1.w;
    float ar0 = acc[r][0]*Ar0.x + acc[r][1]*Ar0.y + acc[r][2]*Ar0.z + acc[r][3]*Ar0.w;
    float ar1 = acc[r][4]*Ar1.x + acc[r][5]*Ar1.y + acc[r][6]*Ar1.z + acc[r][7]*Ar1.w;
#pragma unroll
    for (int off = 1; off < 16; off <<= 1) {
      al0 += __shfl_xor(al0, off);
      al1 += __shfl_xor(al1, off);
      ar0 += __shfl_xor(ar0, off);
      ar1 += __shfl_xor(ar1, off);
    }
    if (cg == 0 && row < N) {
      *(float4*)&alr[(size_t)row * 4] = make_float4(al0, al1, ar0, ar1);
    }
  }
}

__device__ inline void softmax_comb(float& m, float& s, float m2, float s2) {
  float M = fmaxf(m, m2);
  s = s * expf(m - M) + s2 * expf(m2 - M);
  m = M;
}

// ---- per-block online softmax (m,s) partials ----
__global__ __launch_bounds__(256) void alpha_stats_kernel(
    const int* __restrict__ src, const int* __restrict__ dst,
    const float* __restrict__ alr, float* __restrict__ partials, int E) {
  float m0 = -1e30f, s0 = 0.f, m1 = -1e30f, s1 = 0.f;
  for (int e = blockIdx.x * 256 + threadIdx.x; e < E; e += gridDim.x * 256) {
    int sn = src[e], dn = dst[e];
    float4 as = *(const float4*)&alr[(size_t)sn * 4];
    float4 ad = *(const float4*)&alr[(size_t)dn * 4];
    float a0 = as.x + ad.z;
    float a1 = as.y + ad.w;
    a0 = (a0 > 0.f) ? a0 : 0.2f * a0;
    a1 = (a1 > 0.f) ? a1 : 0.2f * a1;
    {
      float M = fmaxf(m0, a0);
      s0 = s0 * expf(m0 - M) + expf(a0 - M);
      m0 = M;
    }
    {
      float M = fmaxf(m1, a1);
      s1 = s1 * expf(m1 - M) + expf(a1 - M);
      m1 = M;
    }
  }
#pragma unroll
  for (int off = 1; off < 64; off <<= 1) {
    float m0o = __shfl_xor(m0, off), s0o = __shfl_xor(s0, off);
    float m1o = __shfl_xor(m1, off), s1o = __shfl_xor(s1, off);
    softmax_comb(m0, s0, m0o, s0o);
    softmax_comb(m1, s1, m1o, s1o);
  }
  __shared__ float red[4][4];
  int wave = threadIdx.x >> 6;
  int lane = threadIdx.x & 63;
  if (lane == 0) {
    red[wave][0] = m0; red[wave][1] = s0; red[wave][2] = m1; red[wave][3] = s1;
  }
  __syncthreads();
  if (threadIdx.x == 0) {
    float M0 = red[0][0], S0 = red[0][1], M1 = red[0][2], S1 = red[0][3];
    for (int w = 1; w < 4; w++) {
      softmax_comb(M0, S0, red[w][0], red[w][1]);
      softmax_comb(M1, S1, red[w][2], red[w][3]);
    }
    float* p = &partials[(size_t)blockIdx.x * 4];
    p[0] = M0; p[1] = S0; p[2] = M1; p[3] = S1;
  }
}

// ---- combine NB_A partials -> stats {M0, 1/S0, M1, 1/S1} ----
__global__ __launch_bounds__(256) void reduce_kernel(
    const float* __restrict__ partials, float* __restrict__ stats) {
  float m0 = -1e30f, s0 = 0.f, m1 = -1e30f, s1 = 0.f;
  for (int i = threadIdx.x; i < NB_A; i += 256) {
    const float* p = &partials[(size_t)i * 4];
    softmax_comb(m0, s0, p[0], p[1]);
    softmax_comb(m1, s1, p[2], p[3]);
  }
#pragma unroll
  for (int off = 1; off < 64; off <<= 1) {
    float m0o = __shfl_xor(m0, off), s0o = __shfl_xor(s0, off);
    float m1o = __shfl_xor(m1, off), s1o = __shfl_xor(s1, off);
    softmax_comb(m0, s0, m0o, s0o);
    softmax_comb(m1, s1, m1o, s1o);
  }
  __shared__ float red[4][4];
  int wave = threadIdx.x >> 6;
  int lane = threadIdx.x & 63;
  if (lane == 0) {
    red[wave][0] = m0; red[wave][1] = s0; red[wave][2] = m1; red[wave][3] = s1;
  }
  __syncthreads();
  if (threadIdx.x == 0) {
    float M0 = red[0][0], S0 = red[0][1], M1 = red[0][2], S1 = red[0][3];
    for (int w = 1; w < 4; w++) {
      softmax_comb(M0, S0, red[w][0], red[w][1]);
      softmax_comb(M1, S1, red[w][2], red[w][3]);
    }
    stats[0] = M0; stats[1] = 1.f / S0;
    stats[2] = M1; stats[3] = 1.f / S1;
  }
}

// ---- bucket histogram: LDS-staged, ~50k global atomics total ----
__global__ __launch_bounds__(256) void hist_kernel(
    const int* __restrict__ dst, int* __restrict__ bucket_cnt, int E, int nb1) {
  __shared__ int hist[MAXB];
  for (int i = threadIdx.x; i < MAXB; i += 256) hist[i] = 0;
  __syncthreads();
  for (int e = blockIdx.x * 256 + threadIdx.x; e < E; e += gridDim.x * 256) {
    atomicAdd(&hist[dst[e] >> BSHIFT], 1);
  }
  __syncthreads();
  for (int b = threadIdx.x; b < nb1; b += 256) {
    int h = hist[b];
    if (h) atomicAdd(&bucket_cnt[b], h);
  }
}

// ---- exclusive scan of bucket counts (nb1 <= 512) ----
__global__ __launch_bounds__(512) void bucket_scan_kernel(
    const int* __restrict__ bucket_cnt, int* __restrict__ bucket_off,
    int* __restrict__ bucket_cursor, int nb1) {
  __shared__ int part[512];
  int t = threadIdx.x;
  int v = (t < nb1) ? bucket_cnt[t] : 0;
  part[t] = v;
  __syncthreads();
  for (int d = 1; d < 512; d <<= 1) {
    int x = (t >= d) ? part[t - d] : 0;
    __syncthreads();
    part[t] += x;
    __syncthreads();
  }
  int excl = part[t] - v;
  if (t < nb1) {
    bucket_off[t] = excl;
    bucket_cursor[t] = excl;
  }
  if (t == 511) bucket_off[nb1] = part[511];  // == E
}

// ---- partition: scatter packed (src | d_local<<17) into bucket regions ----
// Each block reserves contiguous runs per bucket -> writes concentrated in
// time & space (near-1x write amplification vs 16x for per-node scatter).
__global__ __launch_bounds__(256) void partition_kernel(
    const int* __restrict__ src, const int* __restrict__ dst,
    int* __restrict__ bucket_cursor, unsigned int* __restrict__ pairs,
    int E, int nb1, int chunk) {
  __shared__ int hist[MAXB];
  __shared__ int cur[MAXB];
  int base = blockIdx.x * chunk;
  int lim = min(base + chunk, E);
  for (int i = threadIdx.x; i < MAXB; i += 256) hist[i] = 0;
  __syncthreads();
  for (int e = base + threadIdx.x; e < lim; e += 256) {
    atomicAdd(&hist[dst[e] >> BSHIFT], 1);
  }
  __syncthreads();
  for (int b = threadIdx.x; b < nb1; b += 256) {
    cur[b] = atomicAdd(&bucket_cursor[b], hist[b]);
  }
  __syncthreads();
  for (int e = base + threadIdx.x; e < lim; e += 256) {
    int d = dst[e];
    int slot = atomicAdd(&cur[d >> BSHIFT], 1);
    pairs[slot] = (unsigned int)src[e] | ((unsigned int)(d & 255) << 17);
  }
}

// ---- per-bucket CSR: per-node hist+scan -> off[], coalesced edge_src ----
__global__ __launch_bounds__(256) void bucket_csr_kernel(
    const unsigned int* __restrict__ pairs, const int* __restrict__ bucket_off,
    int* __restrict__ off, int* __restrict__ edge_src, int N, int nb1) {
  __shared__ int hist[256];
  __shared__ int cur[256];
  __shared__ int buf[CAP];
  int b = blockIdx.x;
  int t = threadIdx.x;
  int base_node = b << BSHIFT;
  int nn = min(256, N - base_node);
  int pbeg = bucket_off[b], pend = bucket_off[b + 1];
  int cntE = pend - pbeg;

  hist[t] = 0;
  __syncthreads();
  for (int i = t; i < cntE; i += 256) {
    atomicAdd(&hist[pairs[pbeg + i] >> 17], 1);
  }
  __syncthreads();
  int v = hist[t];
  // inclusive scan over 256 entries
  for (int d = 1; d < 256; d <<= 1) {
    int x = (t >= d) ? hist[t - d] : 0;
    __syncthreads();
    hist[t] += x;
    __syncthreads();
  }
  int excl = hist[t] - v;
  cur[t] = excl;
  if (t < nn) off[base_node + t] = pbeg + excl;
  if (b == nb1 - 1 && t == 0) off[N] = pend;
  __syncthreads();
  if (cntE <= CAP) {
    for (int i = t; i < cntE; i += 256) {
      unsigned int p = pairs[pbeg + i];
      int slot = atomicAdd(&cur[p >> 17], 1);
      buf[slot] = (int)(p & 0x1FFFFu);
    }
    __syncthreads();
    for (int i = t; i < cntE; i += 256) {
      edge_src[pbeg + i] = buf[i];
    }
  } else {
    // overflow fallback (statistically never at E/NB1 ~ 4k vs CAP 6144)
    for (int i = t; i < cntE; i += 256) {
      unsigned int p = pairs[pbeg + i];
      int slot = atomicAdd(&cur[p >> 17], 1);
      edge_src[pbeg + slot] = (int)(p & 0x1FFFFu);
    }
  }
}

// ---- gather: one wave per node, 4 edges in flight (4 x 16 lanes), fp16 h ---
__global__ __launch_bounds__(256) void gather_kernel(
    const int* __restrict__ off, const int* __restrict__ edge_src,
    const float* __restrict__ alr, const float* __restrict__ stats,
    const _Float16* __restrict__ h16, float* __restrict__ out, int N) {
  int gid = blockIdx.x * 256 + threadIdx.x;
  int n = gid >> 6;
  if (n >= N) return;
  int lane = threadIdx.x & 63;
  int sub = lane >> 4;   // which of 4 concurrent edges
  int l = lane & 15;     // covers halves [l*8, l*8+8)
  int head = l >> 3;

  float4 ad = *(const float4*)&alr[(size_t)n * 4];
  float adv = head ? ad.w : ad.z;
  float M = stats[head * 2];
  float invS = stats[head * 2 + 1];

  int beg = off[n], end = off[n + 1];
  float acc[8] = {0.f, 0.f, 0.f, 0.f, 0.f, 0.f, 0.f, 0.f};
  for (int i = beg + sub; i < end; i += 4) {
    int sn = edge_src[i];
    float4 as = *(const float4*)&alr[(size_t)sn * 4];
    float a = (head ? as.y : as.x) + adv;
    a = (a > 0.f) ? a : 0.2f * a;
    float w = expf(a - M) * invS;
    half8v hv = *(const half8v*)&h16[(size_t)sn * OCOLS + l * 8];
#pragma unroll
    for (int j = 0; j < 8; j++) acc[j] += w * (float)hv[j];
  }
#pragma unroll
  for (int j = 0; j < 8; j++) {
    acc[j] += __shfl_xor(acc[j], 16);
    acc[j] += __shfl_xor(acc[j], 32);
  }
  if (sub == 0) {
    *(float4*)&out[(size_t)n * OCOLS + l * 8]     = make_float4(acc[0], acc[1], acc[2], acc[3]);
    *(float4*)&out[(size_t)n * OCOLS + l * 8 + 4] = make_float4(acc[4], acc[5], acc[6], acc[7]);
  }
}

extern "C" void kernel_launch(void* const* d_in, const int* in_sizes, int n_in,
                              void* d_out, int out_size, void* d_ws, size_t ws_size,
                              hipStream_t stream) {
  const float* x      = (const float*)d_in[0];
  const int*   edge   = (const int*)d_in[1];   // [2, E]
  const float* W      = (const float*)d_in[2];
  const float* attn_l = (const float*)d_in[3];
  const float* attn_r = (const float*)d_in[4];

  const int N = in_sizes[0] / IN_DIM;
  const int E = in_sizes[1] / 2;
  const int* src = edge;
  const int* dst = edge + E;
  float* out = (float*)d_out;

  const int nb1 = (N + 255) >> BSHIFT;  // 391 for N=100k (<= MAXB)

  // workspace layout
  _Float16*     h16      = (_Float16*)d_ws;                      // N*128 h
  float*        alr      = (float*)(h16 + (size_t)N * OCOLS);    // N*4 f
  float*        partials = alr + (size_t)N * 4;                  // NB_A*4 f
  float*        stats    = partials + (size_t)NB_A * 4;          // 4 f
  int*          bucket_cnt    = (int*)(stats + 4);               // MAXB
  int*          bucket_off    = bucket_cnt + MAXB;               // MAXB+1
  int*          bucket_cursor = bucket_off + MAXB + 1;           // MAXB
  int*          off      = bucket_cursor + MAXB;                 // N+1
  unsigned int* pairs    = (unsigned int*)(off + N + 1);         // E
  int*          edge_src = (int*)(pairs + E);                    // E

  const int chunk = (E + PARTB - 1) / PARTB;

  hipMemsetAsync(bucket_cnt, 0, MAXB * sizeof(int), stream);

  gemm_kernel<<<(N + 63) / 64, 256, 0, stream>>>(x, W, attn_l, attn_r, h16, alr, N);
  hist_kernel<<<HISTB, 256, 0, stream>>>(dst, bucket_cnt, E, nb1);
  alpha_stats_kernel<<<NB_A, 256, 0, stream>>>(src, dst, alr, partials, E);
  reduce_kernel<<<1, 256, 0, stream>>>(partials, stats);
  bucket_scan_kernel<<<1, 512, 0, stream>>>(bucket_cnt, bucket_off, bucket_cursor, nb1);
  partition_kernel<<<PARTB, 256, 0, stream>>>(src, dst, bucket_cursor, pairs, E, nb1, chunk);
  bucket_csr_kernel<<<nb1, 256, 0, stream>>>(pairs, bucket_off, off, edge_src, N, nb1);
  gather_kernel<<<((size_t)N * 64 + 255) / 256, 256, 0, stream>>>(
      off, edge_src, alr, stats, h16, out, N);
}

// Round 6
// 310.629 us; speedup vs baseline: 9.5230x; 1.1586x over previous
//
#include <hip/hip_runtime.h>
#include <hip/hip_fp16.h>
#include <math.h>

#define IN_DIM   128
#define HEADS    2
#define OUT_DIM  64
#define OCOLS    128   // HEADS*OUT_DIM
#define NB_A     1024  // blocks for alpha/softmax partial pass
#define BSHIFT   8     // 256 nodes per bucket
#define MAXB     512   // max buckets (N<=131072)
#define CAP      6144  // bucket_csr LDS buffer capacity (edges); mean 4096
#define HISTB    128   // blocks for hist kernel
#define PARTB    128   // blocks for partition kernel

typedef __attribute__((ext_vector_type(4))) _Float16 half4v;   // 8 B
typedef __attribute__((ext_vector_type(8))) _Float16 half8v;   // 16 B
typedef __attribute__((ext_vector_type(4))) float    floatx4;  // MFMA C/D

// ---- one-time: W[128x128] fp32 -> fp16 packed in MFMA B-fragment order ----
// slot s = (kk*8 + ct)*64 + lane; lane holds B[k][n] for n = ct*16+(lane&15),
// k = kk*32 + (lane>>4)*8 + j, j=0..7  (16x16x32 f16 B-operand layout)
__global__ __launch_bounds__(256) void pack_w_kernel(
    const float* __restrict__ W, half8v* __restrict__ wpack) {
  int t = threadIdx.x;
  for (int s = t; s < 2048; s += 256) {
    int l = s & 63, ct = (s >> 6) & 7, kk = s >> 9;
    int q = l >> 4, n = l & 15;
    int c = ct * 16 + n;
    half8v f;
#pragma unroll
    for (int j = 0; j < 8; j++) {
      f[j] = (_Float16)W[(size_t)(kk * 32 + q * 8 + j) * OCOLS + c];
    }
    wpack[s] = f;
  }
}

// ------- MFMA GEMM + fused epilogue: h16 = fp16(x@W), alr = attn dots ------
// Block: 4 waves x 16 rows = 64 rows, full 128 cols.
// A-frag: lane holds x[row = base + (lane&15)][k = kk*32 + (lane>>4)*8 ..+8]
// C-frag: col = ct*16 + (lane&15), row = base + (lane>>4)*4 + r
__global__ __launch_bounds__(256) void gemm_kernel(
    const float* __restrict__ x, const half8v* __restrict__ wpack,
    const float* __restrict__ attn_l, const float* __restrict__ attn_r,
    _Float16* __restrict__ h16, float* __restrict__ alr, int N) {
  __shared__ half8v Wlds[2048];                     // 32 KB
  __shared__ __align__(16) _Float16 hstage[64 * OCOLS];  // 16 KB
  const int tid = threadIdx.x;
  // coalesced 32 KB copy global -> LDS
  for (int i = tid; i < 2048; i += 256) Wlds[i] = wpack[i];

  const int wave = tid >> 6, lane = tid & 63;
  const int q = lane >> 4, m = lane & 15;
  const int rbase = blockIdx.x * 64 + wave * 16;
  const int arow = rbase + m;
  const bool rok = arow < N;

  // load this lane's x row segments, convert to 4 a-fragments
  half8v a[4];
#pragma unroll
  for (int kk = 0; kk < 4; kk++) {
    float4 u = rok ? *(const float4*)&x[(size_t)arow * IN_DIM + kk * 32 + q * 8]
                   : make_float4(0.f, 0.f, 0.f, 0.f);
    float4 v = rok ? *(const float4*)&x[(size_t)arow * IN_DIM + kk * 32 + q * 8 + 4]
                   : make_float4(0.f, 0.f, 0.f, 0.f);
    a[kk][0] = (_Float16)u.x; a[kk][1] = (_Float16)u.y;
    a[kk][2] = (_Float16)u.z; a[kk][3] = (_Float16)u.w;
    a[kk][4] = (_Float16)v.x; a[kk][5] = (_Float16)v.y;
    a[kk][6] = (_Float16)v.z; a[kk][7] = (_Float16)v.w;
  }
  __syncthreads();  // Wlds ready

  floatx4 acc[8];
#pragma unroll
  for (int ct = 0; ct < 8; ct++) {
    floatx4 c = {0.f, 0.f, 0.f, 0.f};
#pragma unroll
    for (int kk = 0; kk < 4; kk++) {
      c = __builtin_amdgcn_mfma_f32_16x16x32_f16(
          a[kk], Wlds[(kk * 8 + ct) * 64 + lane], c, 0, 0, 0);
    }
    acc[ct] = c;
  }

  // alr from accumulators: lane's cols are ct*16+m; rows q*4+r
  float Al[8], Ar[8];
#pragma unroll
  for (int ct = 0; ct < 8; ct++) {
    Al[ct] = attn_l[ct * 16 + m];
    Ar[ct] = attn_r[ct * 16 + m];
  }
#pragma unroll
  for (int r = 0; r < 4; r++) {
    float al0 = 0.f, al1 = 0.f, ar0 = 0.f, ar1 = 0.f;
#pragma unroll
    for (int ct = 0; ct < 4; ct++) {
      al0 += acc[ct][r] * Al[ct];
      ar0 += acc[ct][r] * Ar[ct];
      al1 += acc[ct + 4][r] * Al[ct + 4];
      ar1 += acc[ct + 4][r] * Ar[ct + 4];
    }
#pragma unroll
    for (int off = 1; off < 16; off <<= 1) {
      al0 += __shfl_xor(al0, off);
      al1 += __shfl_xor(al1, off);
      ar0 += __shfl_xor(ar0, off);
      ar1 += __shfl_xor(ar1, off);
    }
    int orow = rbase + q * 4 + r;
    if (m == 0 && orow < N) {
      *(float4*)&alr[(size_t)orow * 4] = make_float4(al0, al1, ar0, ar1);
    }
  }

  // stage C into LDS (fp16), then coalesced global store
#pragma unroll
  for (int ct = 0; ct < 8; ct++) {
#pragma unroll
    for (int r = 0; r < 4; r++) {
      hstage[(wave * 16 + q * 4 + r) * OCOLS + ct * 16 + m] = (_Float16)acc[ct][r];
    }
  }
  __syncthreads();
  {
    int srow = tid >> 2, seg = tid & 3;
    int grow = blockIdx.x * 64 + srow;
    if (grow < N) {
      const int4* s = (const int4*)&hstage[srow * OCOLS + seg * 32];
      int4* d = (int4*)&h16[(size_t)grow * OCOLS + seg * 32];
      int4 v0 = s[0], v1 = s[1], v2 = s[2], v3 = s[3];
      d[0] = v0; d[1] = v1; d[2] = v2; d[3] = v3;
    }
  }
}

__device__ inline void softmax_comb(float& m, float& s, float m2, float s2) {
  float M = fmaxf(m, m2);
  s = s * expf(m - M) + s2 * expf(m2 - M);
  m = M;
}

// ---- per-block online softmax (m,s) partials ----
__global__ __launch_bounds__(256) void alpha_stats_kernel(
    const int* __restrict__ src, const int* __restrict__ dst,
    const float* __restrict__ alr, float* __restrict__ partials, int E) {
  float m0 = -1e30f, s0 = 0.f, m1 = -1e30f, s1 = 0.f;
  for (int e = blockIdx.x * 256 + threadIdx.x; e < E; e += gridDim.x * 256) {
    int sn = src[e], dn = dst[e];
    float4 as = *(const float4*)&alr[(size_t)sn * 4];
    float4 ad = *(const float4*)&alr[(size_t)dn * 4];
    float a0 = as.x + ad.z;
    float a1 = as.y + ad.w;
    a0 = (a0 > 0.f) ? a0 : 0.2f * a0;
    a1 = (a1 > 0.f) ? a1 : 0.2f * a1;
    {
      float M = fmaxf(m0, a0);
      s0 = s0 * expf(m0 - M) + expf(a0 - M);
      m0 = M;
    }
    {
      float M = fmaxf(m1, a1);
      s1 = s1 * expf(m1 - M) + expf(a1 - M);
      m1 = M;
    }
  }
#pragma unroll
  for (int off = 1; off < 64; off <<= 1) {
    float m0o = __shfl_xor(m0, off), s0o = __shfl_xor(s0, off);
    float m1o = __shfl_xor(m1, off), s1o = __shfl_xor(s1, off);
    softmax_comb(m0, s0, m0o, s0o);
    softmax_comb(m1, s1, m1o, s1o);
  }
  __shared__ float red[4][4];
  int wave = threadIdx.x >> 6;
  int lane = threadIdx.x & 63;
  if (lane == 0) {
    red[wave][0] = m0; red[wave][1] = s0; red[wave][2] = m1; red[wave][3] = s1;
  }
  __syncthreads();
  if (threadIdx.x == 0) {
    float M0 = red[0][0], S0 = red[0][1], M1 = red[0][2], S1 = red[0][3];
    for (int w = 1; w < 4; w++) {
      softmax_comb(M0, S0, red[w][0], red[w][1]);
      softmax_comb(M1, S1, red[w][2], red[w][3]);
    }
    float* p = &partials[(size_t)blockIdx.x * 4];
    p[0] = M0; p[1] = S0; p[2] = M1; p[3] = S1;
  }
}

// ---- combine NB_A partials -> stats {M0, 1/S0, M1, 1/S1} ----
__global__ __launch_bounds__(256) void reduce_kernel(
    const float* __restrict__ partials, float* __restrict__ stats) {
  float m0 = -1e30f, s0 = 0.f, m1 = -1e30f, s1 = 0.f;
  for (int i = threadIdx.x; i < NB_A; i += 256) {
    const float* p = &partials[(size_t)i * 4];
    softmax_comb(m0, s0, p[0], p[1]);
    softmax_comb(m1, s1, p[2], p[3]);
  }
#pragma unroll
  for (int off = 1; off < 64; off <<= 1) {
    float m0o = __shfl_xor(m0, off), s0o = __shfl_xor(s0, off);
    float m1o = __shfl_xor(m1, off), s1o = __shfl_xor(s1, off);
    softmax_comb(m0, s0, m0o, s0o);
    softmax_comb(m1, s1, m1o, s1o);
  }
  __shared__ float red[4][4];
  int wave = threadIdx.x >> 6;
  int lane = threadIdx.x & 63;
  if (lane == 0) {
    red[wave][0] = m0; red[wave][1] = s0; red[wave][2] = m1; red[wave][3] = s1;
  }
  __syncthreads();
  if (threadIdx.x == 0) {
    float M0 = red[0][0], S0 = red[0][1], M1 = red[0][2], S1 = red[0][3];
    for (int w = 1; w < 4; w++) {
      softmax_comb(M0, S0, red[w][0], red[w][1]);
      softmax_comb(M1, S1, red[w][2], red[w][3]);
    }
    stats[0] = M0; stats[1] = 1.f / S0;
    stats[2] = M1; stats[3] = 1.f / S1;
  }
}

// ---- bucket histogram: LDS-staged, ~50k global atomics total ----
__global__ __launch_bounds__(256) void hist_kernel(
    const int* __restrict__ dst, int* __restrict__ bucket_cnt, int E, int nb1) {
  __shared__ int hist[MAXB];
  for (int i = threadIdx.x; i < MAXB; i += 256) hist[i] = 0;
  __syncthreads();
  for (int e = blockIdx.x * 256 + threadIdx.x; e < E; e += gridDim.x * 256) {
    atomicAdd(&hist[dst[e] >> BSHIFT], 1);
  }
  __syncthreads();
  for (int b = threadIdx.x; b < nb1; b += 256) {
    int h = hist[b];
    if (h) atomicAdd(&bucket_cnt[b], h);
  }
}

// ---- exclusive scan of bucket counts (nb1 <= 512) ----
__global__ __launch_bounds__(512) void bucket_scan_kernel(
    const int* __restrict__ bucket_cnt, int* __restrict__ bucket_off,
    int* __restrict__ bucket_cursor, int nb1) {
  __shared__ int part[512];
  int t = threadIdx.x;
  int v = (t < nb1) ? bucket_cnt[t] : 0;
  part[t] = v;
  __syncthreads();
  for (int d = 1; d < 512; d <<= 1) {
    int x = (t >= d) ? part[t - d] : 0;
    __syncthreads();
    part[t] += x;
    __syncthreads();
  }
  int excl = part[t] - v;
  if (t < nb1) {
    bucket_off[t] = excl;
    bucket_cursor[t] = excl;
  }
  if (t == 511) bucket_off[nb1] = part[511];  // == E
}

// ---- partition: scatter packed (src | d_local<<17) into bucket regions ----
__global__ __launch_bounds__(256) void partition_kernel(
    const int* __restrict__ src, const int* __restrict__ dst,
    int* __restrict__ bucket_cursor, unsigned int* __restrict__ pairs,
    int E, int nb1, int chunk) {
  __shared__ int hist[MAXB];
  __shared__ int cur[MAXB];
  int base = blockIdx.x * chunk;
  int lim = min(base + chunk, E);
  for (int i = threadIdx.x; i < MAXB; i += 256) hist[i] = 0;
  __syncthreads();
  for (int e = base + threadIdx.x; e < lim; e += 256) {
    atomicAdd(&hist[dst[e] >> BSHIFT], 1);
  }
  __syncthreads();
  for (int b = threadIdx.x; b < nb1; b += 256) {
    cur[b] = atomicAdd(&bucket_cursor[b], hist[b]);
  }
  __syncthreads();
  for (int e = base + threadIdx.x; e < lim; e += 256) {
    int d = dst[e];
    int slot = atomicAdd(&cur[d >> BSHIFT], 1);
    pairs[slot] = (unsigned int)src[e] | ((unsigned int)(d & 255) << 17);
  }
}

// ---- per-bucket CSR: per-node hist+scan -> off[], coalesced edge_src ----
__global__ __launch_bounds__(256) void bucket_csr_kernel(
    const unsigned int* __restrict__ pairs, const int* __restrict__ bucket_off,
    int* __restrict__ off, int* __restrict__ edge_src, int N, int nb1) {
  __shared__ int hist[256];
  __shared__ int cur[256];
  __shared__ int buf[CAP];
  int b = blockIdx.x;
  int t = threadIdx.x;
  int base_node = b << BSHIFT;
  int nn = min(256, N - base_node);
  int pbeg = bucket_off[b], pend = bucket_off[b + 1];
  int cntE = pend - pbeg;

  hist[t] = 0;
  __syncthreads();
  for (int i = t; i < cntE; i += 256) {
    atomicAdd(&hist[pairs[pbeg + i] >> 17], 1);
  }
  __syncthreads();
  int v = hist[t];
  for (int d = 1; d < 256; d <<= 1) {
    int x = (t >= d) ? hist[t - d] : 0;
    __syncthreads();
    hist[t] += x;
    __syncthreads();
  }
  int excl = hist[t] - v;
  cur[t] = excl;
  if (t < nn) off[base_node + t] = pbeg + excl;
  if (b == nb1 - 1 && t == 0) off[N] = pend;
  __syncthreads();
  if (cntE <= CAP) {
    for (int i = t; i < cntE; i += 256) {
      unsigned int p = pairs[pbeg + i];
      int slot = atomicAdd(&cur[p >> 17], 1);
      buf[slot] = (int)(p & 0x1FFFFu);
    }
    __syncthreads();
    for (int i = t; i < cntE; i += 256) {
      edge_src[pbeg + i] = buf[i];
    }
  } else {
    for (int i = t; i < cntE; i += 256) {
      unsigned int p = pairs[pbeg + i];
      int slot = atomicAdd(&cur[p >> 17], 1);
      edge_src[pbeg + slot] = (int)(p & 0x1FFFFu);
    }
  }
}

// ---- gather: one wave per node, 4 edges in flight (4 x 16 lanes), fp16 h ---
__global__ __launch_bounds__(256) void gather_kernel(
    const int* __restrict__ off, const int* __restrict__ edge_src,
    const float* __restrict__ alr, const float* __restrict__ stats,
    const _Float16* __restrict__ h16, float* __restrict__ out, int N) {
  int gid = blockIdx.x * 256 + threadIdx.x;
  int n = gid >> 6;
  if (n >= N) return;
  int lane = threadIdx.x & 63;
  int sub = lane >> 4;   // which of 4 concurrent edges
  int l = lane & 15;     // covers halves [l*8, l*8+8)
  int head = l >> 3;

  float4 ad = *(const float4*)&alr[(size_t)n * 4];
  float adv = head ? ad.w : ad.z;
  float M = stats[head * 2];
  float invS = stats[head * 2 + 1];

  int beg = off[n], end = off[n + 1];
  float acc[8] = {0.f, 0.f, 0.f, 0.f, 0.f, 0.f, 0.f, 0.f};
  for (int i = beg + sub; i < end; i += 4) {
    int sn = edge_src[i];
    float4 as = *(const float4*)&alr[(size_t)sn * 4];
    float a = (head ? as.y : as.x) + adv;
    a = (a > 0.f) ? a : 0.2f * a;
    float w = expf(a - M) * invS;
    half8v hv = *(const half8v*)&h16[(size_t)sn * OCOLS + l * 8];
#pragma unroll
    for (int j = 0; j < 8; j++) acc[j] += w * (float)hv[j];
  }
#pragma unroll
  for (int j = 0; j < 8; j++) {
    acc[j] += __shfl_xor(acc[j], 16);
    acc[j] += __shfl_xor(acc[j], 32);
  }
  if (sub == 0) {
    *(float4*)&out[(size_t)n * OCOLS + l * 8]     = make_float4(acc[0], acc[1], acc[2], acc[3]);
    *(float4*)&out[(size_t)n * OCOLS + l * 8 + 4] = make_float4(acc[4], acc[5], acc[6], acc[7]);
  }
}

extern "C" void kernel_launch(void* const* d_in, const int* in_sizes, int n_in,
                              void* d_out, int out_size, void* d_ws, size_t ws_size,
                              hipStream_t stream) {
  const float* x      = (const float*)d_in[0];
  const int*   edge   = (const int*)d_in[1];   // [2, E]
  const float* W      = (const float*)d_in[2];
  const float* attn_l = (const float*)d_in[3];
  const float* attn_r = (const float*)d_in[4];

  const int N = in_sizes[0] / IN_DIM;
  const int E = in_sizes[1] / 2;
  const int* src = edge;
  const int* dst = edge + E;
  float* out = (float*)d_out;

  const int nb1 = (N + 255) >> BSHIFT;  // 391 for N=100k (<= MAXB)

  // workspace layout
  _Float16*     h16      = (_Float16*)d_ws;                      // N*128 h
  float*        alr      = (float*)(h16 + (size_t)N * OCOLS);    // N*4 f
  float*        partials = alr + (size_t)N * 4;                  // NB_A*4 f
  float*        stats    = partials + (size_t)NB_A * 4;          // 4 f
  int*          bucket_cnt    = (int*)(stats + 4);               // MAXB
  int*          bucket_off    = bucket_cnt + MAXB;               // MAXB+1
  int*          bucket_cursor = bucket_off + MAXB + 1;           // MAXB
  int*          off      = bucket_cursor + MAXB;                 // N+1
  unsigned int* pairs    = (unsigned int*)(off + N + 1);         // E
  int*          edge_src = (int*)(pairs + E);                    // E
  half8v*       wpack    = (half8v*)(edge_src + E);              // 2048 (32 KB)

  const int chunk = (E + PARTB - 1) / PARTB;

  hipMemsetAsync(bucket_cnt, 0, MAXB * sizeof(int), stream);

  pack_w_kernel<<<1, 256, 0, stream>>>(W, wpack);
  gemm_kernel<<<(N + 63) / 64, 256, 0, stream>>>(x, wpack, attn_l, attn_r, h16, alr, N);
  hist_kernel<<<HISTB, 256, 0, stream>>>(dst, bucket_cnt, E, nb1);
  alpha_stats_kernel<<<NB_A, 256, 0, stream>>>(src, dst, alr, partials, E);
  reduce_kernel<<<1, 256, 0, stream>>>(partials, stats);
  bucket_scan_kernel<<<1, 512, 0, stream>>>(bucket_cnt, bucket_off, bucket_cursor, nb1);
  partition_kernel<<<PARTB, 256, 0, stream>>>(src, dst, bucket_cursor, pairs, E, nb1, chunk);
  bucket_csr_kernel<<<nb1, 256, 0, stream>>>(pairs, bucket_off, off, edge_src, N, nb1);
  gather_kernel<<<((size_t)N * 64 + 255) / 256, 256, 0, stream>>>(
      off, edge_src, alr, stats, h16, out, N);
}

// Round 7
// 283.514 us; speedup vs baseline: 10.4338x; 1.0956x over previous
//
#include <hip/hip_runtime.h>
#include <hip/hip_fp16.h>
#include <math.h>

#define IN_DIM   128
#define HEADS    2
#define OUT_DIM  64
#define OCOLS    128   // HEADS*OUT_DIM
#define NB_A     1024  // blocks for alpha/softmax partial pass
#define BSHIFT   8     // 256 nodes per bucket
#define MAXB     512   // max buckets (N<=131072)
#define PCOPIES  8     // split copies of bucket_cnt (atomic contention / 8)
#define CAP      6144  // bucket_csr LDS buffer capacity (edges); mean 4096
#define PARTB    128   // blocks for partition kernel
#define LOG2E    1.4426950408889634f

typedef __attribute__((ext_vector_type(4))) _Float16 half4v;   // 8 B
typedef __attribute__((ext_vector_type(8))) _Float16 half8v;   // 16 B
typedef __attribute__((ext_vector_type(4))) float    floatx4;  // MFMA C/D

// ---- one-time: W[128x128] fp32 -> fp16 packed in MFMA B-fragment order ----
__global__ __launch_bounds__(256) void pack_w_kernel(
    const float* __restrict__ W, half8v* __restrict__ wpack) {
  int t = threadIdx.x;
  for (int s = t; s < 2048; s += 256) {
    int l = s & 63, ct = (s >> 6) & 7, kk = s >> 9;
    int q = l >> 4, n = l & 15;
    int c = ct * 16 + n;
    half8v f;
#pragma unroll
    for (int j = 0; j < 8; j++) {
      f[j] = (_Float16)W[(size_t)(kk * 32 + q * 8 + j) * OCOLS + c];
    }
    wpack[s] = f;
  }
}

// ------- MFMA GEMM + fused epilogue: h16 = fp16(x@W), alr = attn dots ------
// alr is PRE-SCALED by log2(e) so downstream softmax uses exp2 (1 HW inst).
__global__ __launch_bounds__(256) void gemm_kernel(
    const float* __restrict__ x, const half8v* __restrict__ wpack,
    const float* __restrict__ attn_l, const float* __restrict__ attn_r,
    _Float16* __restrict__ h16, float* __restrict__ alr, int N) {
  __shared__ half8v Wlds[2048];                     // 32 KB
  __shared__ __align__(16) _Float16 hstage[64 * OCOLS];  // 16 KB
  const int tid = threadIdx.x;
  for (int i = tid; i < 2048; i += 256) Wlds[i] = wpack[i];

  const int wave = tid >> 6, lane = tid & 63;
  const int q = lane >> 4, m = lane & 15;
  const int rbase = blockIdx.x * 64 + wave * 16;
  const int arow = rbase + m;
  const bool rok = arow < N;

  half8v a[4];
#pragma unroll
  for (int kk = 0; kk < 4; kk++) {
    float4 u = rok ? *(const float4*)&x[(size_t)arow * IN_DIM + kk * 32 + q * 8]
                   : make_float4(0.f, 0.f, 0.f, 0.f);
    float4 v = rok ? *(const float4*)&x[(size_t)arow * IN_DIM + kk * 32 + q * 8 + 4]
                   : make_float4(0.f, 0.f, 0.f, 0.f);
    a[kk][0] = (_Float16)u.x; a[kk][1] = (_Float16)u.y;
    a[kk][2] = (_Float16)u.z; a[kk][3] = (_Float16)u.w;
    a[kk][4] = (_Float16)v.x; a[kk][5] = (_Float16)v.y;
    a[kk][6] = (_Float16)v.z; a[kk][7] = (_Float16)v.w;
  }
  __syncthreads();  // Wlds ready

  floatx4 acc[8];
#pragma unroll
  for (int ct = 0; ct < 8; ct++) {
    floatx4 c = {0.f, 0.f, 0.f, 0.f};
#pragma unroll
    for (int kk = 0; kk < 4; kk++) {
      c = __builtin_amdgcn_mfma_f32_16x16x32_f16(
          a[kk], Wlds[(kk * 8 + ct) * 64 + lane], c, 0, 0, 0);
    }
    acc[ct] = c;
  }

  float Al[8], Ar[8];
#pragma unroll
  for (int ct = 0; ct < 8; ct++) {
    Al[ct] = attn_l[ct * 16 + m];
    Ar[ct] = attn_r[ct * 16 + m];
  }
#pragma unroll
  for (int r = 0; r < 4; r++) {
    float al0 = 0.f, al1 = 0.f, ar0 = 0.f, ar1 = 0.f;
#pragma unroll
    for (int ct = 0; ct < 4; ct++) {
      al0 += acc[ct][r] * Al[ct];
      ar0 += acc[ct][r] * Ar[ct];
      al1 += acc[ct + 4][r] * Al[ct + 4];
      ar1 += acc[ct + 4][r] * Ar[ct + 4];
    }
#pragma unroll
    for (int off = 1; off < 16; off <<= 1) {
      al0 += __shfl_xor(al0, off);
      al1 += __shfl_xor(al1, off);
      ar0 += __shfl_xor(ar0, off);
      ar1 += __shfl_xor(ar1, off);
    }
    int orow = rbase + q * 4 + r;
    if (m == 0 && orow < N) {
      *(float4*)&alr[(size_t)orow * 4] =
          make_float4(al0 * LOG2E, al1 * LOG2E, ar0 * LOG2E, ar1 * LOG2E);
    }
  }

#pragma unroll
  for (int ct = 0; ct < 8; ct++) {
#pragma unroll
    for (int r = 0; r < 4; r++) {
      hstage[(wave * 16 + q * 4 + r) * OCOLS + ct * 16 + m] = (_Float16)acc[ct][r];
    }
  }
  __syncthreads();
  {
    int srow = tid >> 2, seg = tid & 3;
    int grow = blockIdx.x * 64 + srow;
    if (grow < N) {
      const int4* s = (const int4*)&hstage[srow * OCOLS + seg * 32];
      int4* d = (int4*)&h16[(size_t)grow * OCOLS + seg * 32];
      int4 v0 = s[0], v1 = s[1], v2 = s[2], v3 = s[3];
      d[0] = v0; d[1] = v1; d[2] = v2; d[3] = v3;
    }
  }
}

// online-softmax combiner in log2 domain
__device__ inline void softmax_comb(float& m, float& s, float m2, float s2) {
  float M = fmaxf(m, m2);
  s = s * __builtin_amdgcn_exp2f(m - M) + s2 * __builtin_amdgcn_exp2f(m2 - M);
  m = M;
}

// ---- per-block online softmax partials + bucket histogram (fused) ----
__global__ __launch_bounds__(256) void alpha_stats_kernel(
    const int* __restrict__ src, const int* __restrict__ dst,
    const float* __restrict__ alr, float* __restrict__ partials,
    int* __restrict__ bucket_cnt, int E, int nb1) {
  __shared__ int hist[MAXB];
  for (int i = threadIdx.x; i < MAXB; i += 256) hist[i] = 0;
  __syncthreads();
  const char* ab = (const char*)alr;
  float m0 = -1e30f, s0 = 0.f, m1 = -1e30f, s1 = 0.f;
  for (int e = blockIdx.x * 256 + threadIdx.x; e < E; e += gridDim.x * 256) {
    int sn = src[e], dn = dst[e];
    atomicAdd(&hist[dn >> BSHIFT], 1);
    float4 as = *(const float4*)(ab + ((unsigned)sn << 4));
    float4 ad = *(const float4*)(ab + ((unsigned)dn << 4));
    float a0 = as.x + ad.z;
    float a1 = as.y + ad.w;
    a0 = (a0 > 0.f) ? a0 : 0.2f * a0;
    a1 = (a1 > 0.f) ? a1 : 0.2f * a1;
    {
      float M = fmaxf(m0, a0);
      s0 = s0 * __builtin_amdgcn_exp2f(m0 - M) + __builtin_amdgcn_exp2f(a0 - M);
      m0 = M;
    }
    {
      float M = fmaxf(m1, a1);
      s1 = s1 * __builtin_amdgcn_exp2f(m1 - M) + __builtin_amdgcn_exp2f(a1 - M);
      m1 = M;
    }
  }
  __syncthreads();
  // flush histogram into one of PCOPIES split counters (contention /8)
  for (int b = threadIdx.x; b < nb1; b += 256) {
    int h = hist[b];
    if (h) atomicAdd(&bucket_cnt[(blockIdx.x & (PCOPIES - 1)) * MAXB + b], h);
  }
#pragma unroll
  for (int off = 1; off < 64; off <<= 1) {
    float m0o = __shfl_xor(m0, off), s0o = __shfl_xor(s0, off);
    float m1o = __shfl_xor(m1, off), s1o = __shfl_xor(s1, off);
    softmax_comb(m0, s0, m0o, s0o);
    softmax_comb(m1, s1, m1o, s1o);
  }
  __shared__ float red[4][4];
  int wave = threadIdx.x >> 6;
  int lane = threadIdx.x & 63;
  if (lane == 0) {
    red[wave][0] = m0; red[wave][1] = s0; red[wave][2] = m1; red[wave][3] = s1;
  }
  __syncthreads();
  if (threadIdx.x == 0) {
    float M0 = red[0][0], S0 = red[0][1], M1 = red[0][2], S1 = red[0][3];
    for (int w = 1; w < 4; w++) {
      softmax_comb(M0, S0, red[w][0], red[w][1]);
      softmax_comb(M1, S1, red[w][2], red[w][3]);
    }
    float* p = &partials[(size_t)blockIdx.x * 4];
    p[0] = M0; p[1] = S0; p[2] = M1; p[3] = S1;
  }
}

// ---- combine NB_A partials -> stats {M0, 1/S0, M1, 1/S1} (log2 domain) ----
__global__ __launch_bounds__(256) void reduce_kernel(
    const float* __restrict__ partials, float* __restrict__ stats) {
  float m0 = -1e30f, s0 = 0.f, m1 = -1e30f, s1 = 0.f;
  for (int i = threadIdx.x; i < NB_A; i += 256) {
    const float* p = &partials[(size_t)i * 4];
    softmax_comb(m0, s0, p[0], p[1]);
    softmax_comb(m1, s1, p[2], p[3]);
  }
#pragma unroll
  for (int off = 1; off < 64; off <<= 1) {
    float m0o = __shfl_xor(m0, off), s0o = __shfl_xor(s0, off);
    float m1o = __shfl_xor(m1, off), s1o = __shfl_xor(s1, off);
    softmax_comb(m0, s0, m0o, s0o);
    softmax_comb(m1, s1, m1o, s1o);
  }
  __shared__ float red[4][4];
  int wave = threadIdx.x >> 6;
  int lane = threadIdx.x & 63;
  if (lane == 0) {
    red[wave][0] = m0; red[wave][1] = s0; red[wave][2] = m1; red[wave][3] = s1;
  }
  __syncthreads();
  if (threadIdx.x == 0) {
    float M0 = red[0][0], S0 = red[0][1], M1 = red[0][2], S1 = red[0][3];
    for (int w = 1; w < 4; w++) {
      softmax_comb(M0, S0, red[w][0], red[w][1]);
      softmax_comb(M1, S1, red[w][2], red[w][3]);
    }
    stats[0] = M0; stats[1] = 1.f / S0;
    stats[2] = M1; stats[3] = 1.f / S1;
  }
}

// ---- exclusive scan of bucket counts (sums PCOPIES split counters) ----
__global__ __launch_bounds__(512) void bucket_scan_kernel(
    const int* __restrict__ bucket_cnt, int* __restrict__ bucket_off,
    int* __restrict__ bucket_cursor, int nb1) {
  __shared__ int part[512];
  int t = threadIdx.x;
  int v = 0;
  if (t < nb1) {
#pragma unroll
    for (int c = 0; c < PCOPIES; c++) v += bucket_cnt[c * MAXB + t];
  }
  part[t] = v;
  __syncthreads();
  for (int d = 1; d < 512; d <<= 1) {
    int x = (t >= d) ? part[t - d] : 0;
    __syncthreads();
    part[t] += x;
    __syncthreads();
  }
  int excl = part[t] - v;
  if (t < nb1) {
    bucket_off[t] = excl;
    bucket_cursor[t] = excl;
  }
  if (t == 511) bucket_off[nb1] = part[511];  // == E
}

// ---- partition: scatter packed (src | d_local<<17) into bucket regions ----
__global__ __launch_bounds__(256) void partition_kernel(
    const int* __restrict__ src, const int* __restrict__ dst,
    int* __restrict__ bucket_cursor, unsigned int* __restrict__ pairs,
    int E, int nb1, int chunk) {
  __shared__ int hist[MAXB];
  __shared__ int cur[MAXB];
  int base = blockIdx.x * chunk;
  int lim = min(base + chunk, E);
  for (int i = threadIdx.x; i < MAXB; i += 256) hist[i] = 0;
  __syncthreads();
  for (int e = base + threadIdx.x; e < lim; e += 256) {
    atomicAdd(&hist[dst[e] >> BSHIFT], 1);
  }
  __syncthreads();
  for (int b = threadIdx.x; b < nb1; b += 256) {
    cur[b] = atomicAdd(&bucket_cursor[b], hist[b]);
  }
  __syncthreads();
  for (int e = base + threadIdx.x; e < lim; e += 256) {
    int d = dst[e];
    int slot = atomicAdd(&cur[d >> BSHIFT], 1);
    pairs[slot] = (unsigned int)src[e] | ((unsigned int)(d & 255) << 17);
  }
}

// ---- per-bucket CSR: per-node hist+scan -> off[], coalesced edge_src ----
__global__ __launch_bounds__(256) void bucket_csr_kernel(
    const unsigned int* __restrict__ pairs, const int* __restrict__ bucket_off,
    int* __restrict__ off, int* __restrict__ edge_src, int N, int nb1) {
  __shared__ int hist[256];
  __shared__ int cur[256];
  __shared__ int buf[CAP];
  int b = blockIdx.x;
  int t = threadIdx.x;
  int base_node = b << BSHIFT;
  int nn = min(256, N - base_node);
  int pbeg = bucket_off[b], pend = bucket_off[b + 1];
  int cntE = pend - pbeg;

  hist[t] = 0;
  __syncthreads();
  for (int i = t; i < cntE; i += 256) {
    atomicAdd(&hist[pairs[pbeg + i] >> 17], 1);
  }
  __syncthreads();
  int v = hist[t];
  for (int d = 1; d < 256; d <<= 1) {
    int x = (t >= d) ? hist[t - d] : 0;
    __syncthreads();
    hist[t] += x;
    __syncthreads();
  }
  int excl = hist[t] - v;
  cur[t] = excl;
  if (t < nn) off[base_node + t] = pbeg + excl;
  if (b == nb1 - 1 && t == 0) off[N] = pend;
  __syncthreads();
  if (cntE <= CAP) {
    for (int i = t; i < cntE; i += 256) {
      unsigned int p = pairs[pbeg + i];
      int slot = atomicAdd(&cur[p >> 17], 1);
      buf[slot] = (int)(p & 0x1FFFFu);
    }
    __syncthreads();
    for (int i = t; i < cntE; i += 256) {
      edge_src[pbeg + i] = buf[i];
    }
  } else {
    for (int i = t; i < cntE; i += 256) {
      unsigned int p = pairs[pbeg + i];
      int slot = atomicAdd(&cur[p >> 17], 1);
      edge_src[pbeg + slot] = (int)(p & 0x1FFFFu);
    }
  }
}

// ---- gather: one wave per node, 4x16 lanes, unroll x2, exp2, u32 addrs ----
__global__ __launch_bounds__(256) void gather_kernel(
    const int* __restrict__ off, const int* __restrict__ edge_src,
    const float* __restrict__ alr, const float* __restrict__ stats,
    const _Float16* __restrict__ h16, float* __restrict__ out, int N) {
  int gid = blockIdx.x * 256 + threadIdx.x;
  int n = gid >> 6;
  if (n >= N) return;
  int lane = threadIdx.x & 63;
  int sub = lane >> 4;   // which of 4 concurrent edges
  int l = lane & 15;     // covers halves [l*8, l*8+8)
  int head = l >> 3;

  const char* ab = (const char*)alr;
  const char* hb = (const char*)h16;
  float4 ad = *(const float4*)(ab + ((unsigned)n << 4));
  float adv = head ? ad.w : ad.z;
  float M = stats[head * 2];
  float invS = stats[head * 2 + 1];
  unsigned loff = (unsigned)l * 16u;

  int beg = off[n], end = off[n + 1];
  float acc[8] = {0.f, 0.f, 0.f, 0.f, 0.f, 0.f, 0.f, 0.f};
  int i = beg + sub;
  for (; i + 4 < end; i += 8) {
    int sn0 = edge_src[i], sn1 = edge_src[i + 4];
    float4 as0 = *(const float4*)(ab + ((unsigned)sn0 << 4));
    float4 as1 = *(const float4*)(ab + ((unsigned)sn1 << 4));
    half8v hv0 = *(const half8v*)(hb + (((unsigned)sn0 << 8) + loff));
    half8v hv1 = *(const half8v*)(hb + (((unsigned)sn1 << 8) + loff));
    float a0 = (head ? as0.y : as0.x) + adv;
    float a1 = (head ? as1.y : as1.x) + adv;
    a0 = (a0 > 0.f) ? a0 : 0.2f * a0;
    a1 = (a1 > 0.f) ? a1 : 0.2f * a1;
    float w0 = __builtin_amdgcn_exp2f(a0 - M) * invS;
    float w1 = __builtin_amdgcn_exp2f(a1 - M) * invS;
#pragma unroll
    for (int j = 0; j < 8; j++) acc[j] += w0 * (float)hv0[j];
#pragma unroll
    for (int j = 0; j < 8; j++) acc[j] += w1 * (float)hv1[j];
  }
  if (i < end) {
    int sn = edge_src[i];
    float4 as = *(const float4*)(ab + ((unsigned)sn << 4));
    half8v hv = *(const half8v*)(hb + (((unsigned)sn << 8) + loff));
    float a = (head ? as.y : as.x) + adv;
    a = (a > 0.f) ? a : 0.2f * a;
    float w = __builtin_amdgcn_exp2f(a - M) * invS;
#pragma unroll
    for (int j = 0; j < 8; j++) acc[j] += w * (float)hv[j];
  }
#pragma unroll
  for (int j = 0; j < 8; j++) {
    acc[j] += __shfl_xor(acc[j], 16);
    acc[j] += __shfl_xor(acc[j], 32);
  }
  if (sub == 0) {
    char* ob = (char*)out;
    unsigned obase = ((unsigned)n << 9) + (unsigned)l * 32u;
    *(float4*)(ob + obase)      = make_float4(acc[0], acc[1], acc[2], acc[3]);
    *(float4*)(ob + obase + 16) = make_float4(acc[4], acc[5], acc[6], acc[7]);
  }
}

extern "C" void kernel_launch(void* const* d_in, const int* in_sizes, int n_in,
                              void* d_out, int out_size, void* d_ws, size_t ws_size,
                              hipStream_t stream) {
  const float* x      = (const float*)d_in[0];
  const int*   edge   = (const int*)d_in[1];   // [2, E]
  const float* W      = (const float*)d_in[2];
  const float* attn_l = (const float*)d_in[3];
  const float* attn_r = (const float*)d_in[4];

  const int N = in_sizes[0] / IN_DIM;
  const int E = in_sizes[1] / 2;
  const int* src = edge;
  const int* dst = edge + E;
  float* out = (float*)d_out;

  const int nb1 = (N + 255) >> BSHIFT;  // 391 for N=100k (<= MAXB)

  // workspace layout
  _Float16*     h16      = (_Float16*)d_ws;                      // N*128 h
  float*        alr      = (float*)(h16 + (size_t)N * OCOLS);    // N*4 f
  float*        partials = alr + (size_t)N * 4;                  // NB_A*4 f
  float*        stats    = partials + (size_t)NB_A * 4;          // 4 f
  int*          bucket_cnt    = (int*)(stats + 4);               // PCOPIES*MAXB
  int*          bucket_off    = bucket_cnt + PCOPIES * MAXB;     // MAXB+1
  int*          bucket_cursor = bucket_off + MAXB + 1;           // MAXB
  int*          off      = bucket_cursor + MAXB;                 // N+1
  unsigned int* pairs    = (unsigned int*)(off + N + 1);         // E
  int*          edge_src = (int*)(pairs + E);                    // E
  half8v*       wpack    = (half8v*)(edge_src + E);              // 2048 (32 KB)

  const int chunk = (E + PARTB - 1) / PARTB;

  hipMemsetAsync(bucket_cnt, 0, PCOPIES * MAXB * sizeof(int), stream);

  pack_w_kernel<<<1, 256, 0, stream>>>(W, wpack);
  gemm_kernel<<<(N + 63) / 64, 256, 0, stream>>>(x, wpack, attn_l, attn_r, h16, alr, N);
  alpha_stats_kernel<<<NB_A, 256, 0, stream>>>(src, dst, alr, partials, bucket_cnt, E, nb1);
  reduce_kernel<<<1, 256, 0, stream>>>(partials, stats);
  bucket_scan_kernel<<<1, 512, 0, stream>>>(bucket_cnt, bucket_off, bucket_cursor, nb1);
  partition_kernel<<<PARTB, 256, 0, stream>>>(src, dst, bucket_cursor, pairs, E, nb1, chunk);
  bucket_csr_kernel<<<nb1, 256, 0, stream>>>(pairs, bucket_off, off, edge_src, N, nb1);
  gather_kernel<<<((size_t)N * 64 + 255) / 256, 256, 0, stream>>>(
      off, edge_src, alr, stats, h16, out, N);
}